// Round 2
// baseline (642.410 us; speedup 1.0000x reference)
//
#include <hip/hip_runtime.h>
#include <hip/hip_bf16.h>

typedef __bf16 bf16;
typedef __bf16 bf16x2 __attribute__((ext_vector_type(2)));
typedef __bf16 bf16x4 __attribute__((ext_vector_type(4)));
typedef __bf16 bf16x8 __attribute__((ext_vector_type(8)));
typedef float  f32x4  __attribute__((ext_vector_type(4)));
typedef unsigned int u32x4 __attribute__((ext_vector_type(4)));

#define H_   2048
#define S_   2048
#define B_   2
#define NH_  16
#define NKV_ 4
#define HD_  128
#define KVS  1024   /* fused K|V row width */

// 1/sqrt(HD) * log2(e): folded into Q so attention can use exp2 directly
#define QSCALE 0.12751743f

__device__ __forceinline__ f32x4 mfma16(bf16x8 a, bf16x8 b, f32x4 c) {
  return __builtin_amdgcn_mfma_f32_16x16x32_bf16(a, b, c, 0, 0, 0);
}

// async global->LDS, 16B per lane (m97 pattern; LDS dst lane-contiguous)
typedef __attribute__((address_space(3))) unsigned int lds_u32_t;
typedef const __attribute__((address_space(1))) unsigned int glb_u32_t;
__device__ __forceinline__ void glds16(const bf16* g, bf16* l) {
  __builtin_amdgcn_global_load_lds((glb_u32_t*)g, (lds_u32_t*)l, 16, 0, 0);
}

// pack two f32 -> one dword of 2 bf16 (lo = first arg)
__device__ __forceinline__ unsigned pk2(float a, float b) {
  bf16x2 v = { (bf16)a, (bf16)b };
  return __builtin_bit_cast(unsigned, v);
}

// ---------------------------------------------------------------------------
// PREP mega-kernel: both activation converts + all six weight transposes in
// ONE launch (they are mutually independent, inputs-only). 1-D grid, ranges:
//   [0,8192)      hidden -> hb   (fp32->bf16, 1024 elems/block)
//   [8192,16384)  source -> sb
//   [16384,+4096) Wq^T  [+4096) W1^T  [+4096) W2^T  [+4096) Wd^T
//   [+1024) Wk^T  [+1024) Wv^T
// ---------------------------------------------------------------------------
__global__ __launch_bounds__(256)
void prep(const float* __restrict__ Wq, const float* __restrict__ W1,
          const float* __restrict__ W2, const float* __restrict__ Wd,
          const float* __restrict__ Wk, const float* __restrict__ Wv,
          const float* __restrict__ hidden, const float* __restrict__ source,
          bf16* __restrict__ Wqt, bf16* __restrict__ W1t,
          bf16* __restrict__ W2t, bf16* __restrict__ Wdt,
          bf16* __restrict__ Wkt, bf16* __restrict__ Wvt,
          bf16* __restrict__ hb,  bf16* __restrict__ sb)
{
  __shared__ bf16 t[32][33];
  int idx = blockIdx.x;
  if (idx < 16384) {                       // activation converts
    const float* in = (idx < 8192) ? hidden : source;
    bf16*       out = (idx < 8192) ? hb : sb;
    const int i = idx & 8191;
    const size_t off = ((size_t)i * 256 + threadIdx.x) * 4;
    const float4 v = *(const float4*)(in + off);
    bf16x4 o = { (bf16)v.x, (bf16)v.y, (bf16)v.z, (bf16)v.w };
    *(bf16x4*)(out + off) = o;
    return;
  }
  idx -= 16384;
  const float* in; bf16* out; int N;
  if      (idx < 4096)  { in = Wq; out = Wqt; N = 2048; }
  else if (idx < 8192)  { in = W1; out = W1t; N = 2048; idx -= 4096; }
  else if (idx < 12288) { in = W2; out = W2t; N = 2048; idx -= 8192; }
  else if (idx < 16384) { in = Wd; out = Wdt; N = 2048; idx -= 12288; }
  else if (idx < 17408) { in = Wk; out = Wkt; N = 512;  idx -= 16384; }
  else                  { in = Wv; out = Wvt; N = 512;  idx -= 17408; }
  const int K = 2048;
  const int tx = threadIdx.x & 31, ty = threadIdx.x >> 5;
  const int k0 = (idx & 63) * 32, n0 = (idx >> 6) * 32;
  #pragma unroll
  for (int i = 0; i < 4; i++)
    t[ty + i*8][tx] = (bf16)in[(size_t)(k0 + ty + i*8) * N + n0 + tx];
  __syncthreads();
  #pragma unroll
  for (int i = 0; i < 4; i++)
    out[(size_t)(n0 + ty + i*8) * K + k0 + tx] = t[tx][ty + i*8];
}

// ---------------------------------------------------------------------------
// V half of fused KV [b, s, 1024] -> Vt [b, kv, d, s]
// ---------------------------------------------------------------------------
__global__ __launch_bounds__(256)
void transpose_v(const bf16* __restrict__ KVin, bf16* __restrict__ Vt)
{
  __shared__ bf16 t[32][33];
  const int tx = threadIdx.x & 31, ty = threadIdx.x >> 5;
  const int s0 = blockIdx.x * 32, d0 = blockIdx.y * 32;
  const int bk = blockIdx.z;
  const int b = bk >> 2, kv = bk & 3;
  const bf16* src = KVin + (size_t)b * S_ * KVS + 512 + kv * HD_;
  #pragma unroll
  for (int i = 0; i < 4; i++)
    t[ty + i*8][tx] = src[(size_t)(s0 + ty + i*8) * KVS + d0 + tx];
  __syncthreads();
  bf16* dst = Vt + (size_t)bk * HD_ * S_;
  #pragma unroll
  for (int i = 0; i < 4; i++)
    dst[(size_t)(d0 + ty + i*8) * S_ + s0 + tx] = t[tx][ty + i*8];
}

// ---------------------------------------------------------------------------
// 128x128-tile bf16 MFMA GEMM body, double-buffered glds16 staging.
// bias split: col < nsplit -> bias[col], else bias2[col-nsplit] (fused KV).
// ---------------------------------------------------------------------------
__device__ __forceinline__
void gemm_body(const bf16* __restrict__ A, const bf16* __restrict__ Wt,
               const float* __restrict__ bias, const float* __restrict__ bias2,
               int nsplit, const bf16* __restrict__ resid,
               bf16* __restrict__ outB, int N, int K, int relu, float oscale,
               int m0, int n0, bf16* As, bf16* Bs)
{
  const int tid  = threadIdx.x;
  const int lane = tid & 63;
  const int w    = tid >> 6;
  const int wm = w & 1, wn = w >> 1;
  const int quad = lane >> 4, l16 = lane & 15;
  const int g_r = lane >> 2;
  const int g_c = (lane & 3) * 8;

  const f32x4 fz = {0.f, 0.f, 0.f, 0.f};
  f32x4 acc[4][4];
  #pragma unroll
  for (int i = 0; i < 4; i++)
    #pragma unroll
    for (int j = 0; j < 4; j++) acc[i][j] = fz;

  auto stage = [&](int nb, int k0) {
    #pragma unroll
    for (int i = 0; i < 2; i++) {
      const int rb = (w*2 + i) * 16;
      glds16(A  + (size_t)(m0 + rb + g_r) * K + k0 + g_c, As + nb*4096 + rb*32 + lane*8);
      glds16(Wt + (size_t)(n0 + rb + g_r) * K + k0 + g_c, Bs + nb*4096 + rb*32 + lane*8);
    }
  };

  stage(0, 0);
  const int NK = K >> 5;
  for (int it = 0; it < NK; it++) {
    const int bf = it & 1;
    __syncthreads();
    if (it + 1 < NK) stage(bf ^ 1, (it + 1) << 5);
    bf16x8 af[4], bfr[4];
    #pragma unroll
    for (int i = 0; i < 4; i++)
      af[i]  = *(const bf16x8*)(As + bf*4096 + (wm*64 + i*16 + l16)*32 + quad*8);
    #pragma unroll
    for (int j = 0; j < 4; j++)
      bfr[j] = *(const bf16x8*)(Bs + bf*4096 + (wn*64 + j*16 + l16)*32 + quad*8);
    #pragma unroll
    for (int i = 0; i < 4; i++)
      #pragma unroll
      for (int j = 0; j < 4; j++)
        acc[i][j] = mfma16(af[i], bfr[j], acc[i][j]);
  }

  // C/D layout: col = lane&15, row = (lane>>4)*4 + reg   [m89/m91]
  #pragma unroll
  for (int i = 0; i < 4; i++) {
    const int row = m0 + wm*64 + i*16 + quad*4;
    #pragma unroll
    for (int j = 0; j < 4; j++) {
      const int col = n0 + wn*64 + j*16 + l16;
      const float bi = (col < nsplit) ? bias[col] : bias2[col - nsplit];
      #pragma unroll
      for (int r = 0; r < 4; r++) {
        float v = acc[i][j][r] + bi;
        if (relu) v = fmaxf(v, 0.f);
        v *= oscale;
        size_t idx = (size_t)(row + r) * N + col;
        if (resid) v += (float)resid[idx];
        outB[idx] = (bf16)v;
      }
    }
  }
}

__global__ __launch_bounds__(256)
void gemm_one(const bf16* __restrict__ A, const bf16* __restrict__ Wt,
              const float* __restrict__ bias, const float* __restrict__ bias2,
              int nsplit, const bf16* __restrict__ resid,
              bf16* __restrict__ outB, int N, int K, int relu, float oscale)
{
  __shared__ __align__(16) bf16 As[2*128*32];
  __shared__ __align__(16) bf16 Bs[2*128*32];
  gemm_body(A, Wt, bias, bias2, nsplit, resid, outB, N, K, relu, oscale,
            blockIdx.y*128, blockIdx.x*128, As, Bs);
}

// Two independent GEMMs in one launch (z selects): Q-proj and lin1.
__global__ __launch_bounds__(256)
void gemm_dual(const bf16* __restrict__ A0, const bf16* __restrict__ W0,
               const float* __restrict__ b0, bf16* __restrict__ o0,
               int relu0, float s0,
               const bf16* __restrict__ A1, const bf16* __restrict__ W1,
               const float* __restrict__ b1, bf16* __restrict__ o1,
               int relu1, float s1, int N, int K)
{
  __shared__ __align__(16) bf16 As[2*128*32];
  __shared__ __align__(16) bf16 Bs[2*128*32];
  if (blockIdx.z == 0)
    gemm_body(A0, W0, b0, b0, 1<<30, nullptr, o0, N, K, relu0, s0,
              blockIdx.y*128, blockIdx.x*128, As, Bs);
  else
    gemm_body(A1, W1, b1, b1, 1<<30, nullptr, o1, N, K, relu1, s1,
              blockIdx.y*128, blockIdx.x*128, As, Bs);
}

// ---------------------------------------------------------------------------
// GQA attention PARTIAL, round-10:
//  * swapped QK^T (mfma(K,Q)) -> P lands q=lane&15, s in regs.
//  * PV A-fragment built IN-REGISTER via pull-model __shfl transpose
//    (8 bpermutes + 4 selects per i-tile) -- Ps LDS array deleted.
//  * K/V staged in FRAGMENT-MAJOR LDS layout (glds16 writes lane*16B
//    linearly; global source pre-permuted so chunk byte l*16 holds exactly
//    the fragment data lane l reads back). All ds_read_b128 lane-linear ->
//    conflict-free.
//  * LDS 43008 -> 32768 B; __launch_bounds__(256,4) -> 4 blocks/CU.
//  * s_setprio(1) around both MFMA clusters (T5).
// Grid (16 qt, 16 h, B*2 s-halves) = 1024 blocks.
// ---------------------------------------------------------------------------
__global__ __launch_bounds__(256, 4)
void attn_partial(const bf16* __restrict__ Q, const bf16* __restrict__ KV,
                  const bf16* __restrict__ Vt, bf16* __restrict__ OpBase,
                  float* __restrict__ LsBase)
{
  // Ks: [buf][kt*2+half][lane][8]  (chunk = one 16s x 32d K fragment, 1KB)
  // Vs: [buf][nt]       [lane][8]  (chunk = one 16d x 32s V^T fragment)
  __shared__ __align__(16) bf16 Ks[2*4096];
  __shared__ __align__(16) bf16 Vs[2*4096];
  const int tid = threadIdx.x;
  const int lane = tid & 63, w = tid >> 6;
  const int quad = lane >> 4, l16 = lane & 15;
  const int qt = blockIdx.x, h = blockIdx.y;
  const int b = blockIdx.z >> 1, sh = blockIdx.z & 1;
  const int kv = h >> 2;                 // G = 4
  const int qbase = qt * 128 + w * 32;
  const int s_begin = sh * (S_/2);

  bf16*  Op = OpBase + (size_t)sh * 8388608;        // +16 MiB half stride
  float* Lp = LsBase + (size_t)sh * (B_*NH_*S_);

  const bf16* Qp = Q  + ((size_t)b * S_ + qbase) * H_ + h * HD_;
  const bf16* Kp = KV + (size_t)b * S_ * KVS + kv * HD_;
  const bf16* Vp = Vt + (size_t)(b * NKV_ + kv) * HD_ * S_;

  // fragment-row / fragment-col for pre-permuted staging source
  const int fr = lane & 15;
  const int fc = (lane >> 4) * 8;

  const f32x4 fz = {0.f, 0.f, 0.f, 0.f};

  bf16x8 qf[2][4];
  #pragma unroll
  for (int i = 0; i < 2; i++)
    #pragma unroll
    for (int kt = 0; kt < 4; kt++)
      qf[i][kt] = *(const bf16x8*)(Qp + (size_t)(i*16 + l16) * H_ + kt*32 + quad*8);

  f32x4 o[2][8];
  #pragma unroll
  for (int i = 0; i < 2; i++)
    #pragma unroll
    for (int n = 0; n < 8; n++) o[i][n] = fz;
  float lsum[2] = {0.f, 0.f};

  // wave w stages K fragments (kt=w, halves 0/1) and V fragments (nt=w, 4+w)
  auto stageKV = [&](int nb, int s0) {
    bf16* Kb = Ks + nb*4096;
    bf16* Vb = Vs + nb*4096;
    glds16(Kp + (size_t)(s0 +      fr) * KVS + w*32 + fc, Kb + (w*2+0)*512 + lane*8);
    glds16(Kp + (size_t)(s0 + 16 + fr) * KVS + w*32 + fc, Kb + (w*2+1)*512 + lane*8);
    glds16(Vp + (size_t)(w*16     + fr) * S_ + s0 + fc,   Vb + w*512       + lane*8);
    glds16(Vp + (size_t)((4+w)*16 + fr) * S_ + s0 + fc,   Vb + (4+w)*512   + lane*8);
  };

  stageKV(0, s_begin);

  const int NIT = (S_/2) / 32;   // 32
  for (int it = 0; it < NIT; it++) {
    const int bf = it & 1;
    __syncthreads();
    if (it + 1 < NIT) stageKV(bf ^ 1, s_begin + (it + 1) * 32);

    // ---- QK^T, swapped operands: sa[i][half] has q=l16, s=half*16+quad*4+r
    const bf16* Kb = Ks + bf*4096;
    f32x4 sa[2][2];
    sa[0][0] = fz; sa[0][1] = fz; sa[1][0] = fz; sa[1][1] = fz;
    __builtin_amdgcn_s_setprio(1);
    #pragma unroll
    for (int kt = 0; kt < 4; kt++) {
      bf16x8 kf0 = *(const bf16x8*)(Kb + (kt*2+0)*512 + lane*8);
      bf16x8 kf1 = *(const bf16x8*)(Kb + (kt*2+1)*512 + lane*8);
      #pragma unroll
      for (int i = 0; i < 2; i++) {
        sa[i][0] = mfma16(kf0, qf[i][kt], sa[i][0]);
        sa[i][1] = mfma16(kf1, qf[i][kt], sa[i][1]);
      }
    }
    __builtin_amdgcn_s_setprio(0);

    // ---- softmax numerator + in-register transpose to PV A-fragments
    bf16x8 pf[2];
    #pragma unroll
    for (int i = 0; i < 2; i++) {
      float p[2][4];
      #pragma unroll
      for (int nt = 0; nt < 2; nt++)
        #pragma unroll
        for (int r = 0; r < 4; r++) {
          p[nt][r] = exp2f(sa[i][nt][r]);   // Q pre-scaled by 1/sqrt(d)*log2e
          lsum[i] += p[nt][r];
        }
      // source: lane (q=l16, quad') holds s = quad'*4+r (nt0), 16+quad'*4+r (nt1)
      unsigned Apk = pk2(p[0][0], p[0][1]);   // s = q'*4 + {0,1}
      unsigned Bpk = pk2(p[0][2], p[0][3]);   // s = q'*4 + {2,3}
      unsigned Cpk = pk2(p[1][0], p[1][1]);   // s = 16 + q'*4 + {0,1}
      unsigned Dpk = pk2(p[1][2], p[1][3]);   // s = 16 + q'*4 + {2,3}
      // target: lane (q=l16, quad) needs s = quad*8 + 0..7 as 4 dwords.
      //   quad0: A,B from q'0 then q'1 | quad1: A,B from q'2 then q'3
      //   quad2: C,D from q'0 then q'1 | quad3: C,D from q'2 then q'3
      const int srcL = l16 + ((quad & 1) << 5);   // lane of quad' = 2*(quad&1)
      const bool hi = (quad >= 2);
      const unsigned a0 = __shfl(Apk, srcL),      b0 = __shfl(Bpk, srcL);
      const unsigned a1 = __shfl(Apk, srcL + 16), b1 = __shfl(Bpk, srcL + 16);
      const unsigned c0 = __shfl(Cpk, srcL),      d0 = __shfl(Dpk, srcL);
      const unsigned c1 = __shfl(Cpk, srcL + 16), d1 = __shfl(Dpk, srcL + 16);
      u32x4 t;
      t.x = hi ? c0 : a0;
      t.y = hi ? d0 : b0;
      t.z = hi ? c1 : a1;
      t.w = hi ? d1 : b1;
      pf[i] = __builtin_bit_cast(bf16x8, t);
    }

    // ---- PV
    const bf16* Vb = Vs + bf*4096;
    __builtin_amdgcn_s_setprio(1);
    #pragma unroll
    for (int nt = 0; nt < 8; nt++) {
      bf16x8 vf = *(const bf16x8*)(Vb + nt*512 + lane*8);
      o[0][nt] = mfma16(pf[0], vf, o[0][nt]);
      o[1][nt] = mfma16(pf[1], vf, o[1][nt]);
    }
    __builtin_amdgcn_s_setprio(0);
  }

  bf16* op = Op + ((size_t)b * S_ + qbase) * H_ + h * HD_;
  #pragma unroll
  for (int i = 0; i < 2; i++)
    #pragma unroll
    for (int nt = 0; nt < 8; nt++)
      #pragma unroll
      for (int r = 0; r < 4; r++)
        op[(size_t)(i*16 + quad*4 + r) * H_ + nt*16 + l16] = (bf16)o[i][nt][r];

  // row-sums: lane holds partial over its 8 s-values; reduce across quads
  float* lp = Lp + (size_t)(b * NH_ + h) * S_ + qbase;
  #pragma unroll
  for (int i = 0; i < 2; i++) {
    float s = lsum[i];
    s += __shfl_xor(s, 16);
    s += __shfl_xor(s, 32);
    if (lane < 16) lp[i*16 + lane] = s;
  }
}

// ---------------------------------------------------------------------------
// ctx = (O0+O1)/(L0+L1); one block per (b,s) row.
// ---------------------------------------------------------------------------
__global__ __launch_bounds__(256)
void attn_combine(const bf16* __restrict__ O0, const bf16* __restrict__ O1,
                  const float* __restrict__ L0, const float* __restrict__ L1,
                  bf16* __restrict__ ctx)
{
  const int row = blockIdx.x;              // b*S + s
  const int b = row >> 11, s = row & 2047;
  const int tid = threadIdx.x;
  const int h = tid >> 4;
  const size_t idx = (size_t)row * H_ + tid * 8;
  const size_t li  = (size_t)(b * NH_ + h) * S_ + s;
  const float rinv = 1.f / (L0[li] + L1[li]);
  bf16x8 a = *(const bf16x8*)(O0 + idx);
  bf16x8 c = *(const bf16x8*)(O1 + idx);
  bf16x8 o;
  #pragma unroll
  for (int k = 0; k < 8; k++)
    o[k] = (bf16)(((float)a[k] + (float)c[k]) * rinv);
  *(bf16x8*)(ctx + idx) = o;
}

// ---------------------------------------------------------------------------
// y = LN(a + hidden)*gamma + beta. fp32 out.
// ---------------------------------------------------------------------------
__global__ __launch_bounds__(256)
void ln_fused(const bf16* __restrict__ a, const float* __restrict__ hidden,
              const float* __restrict__ gamma, const float* __restrict__ beta,
              float* __restrict__ out)
{
  __shared__ float red[8];
  const int row = blockIdx.x;
  const bf16*  pa = a      + (size_t)row * H_;
  const float* pb = hidden + (size_t)row * H_;
  float x[8]; float s = 0.f, s2 = 0.f;
  #pragma unroll
  for (int j = 0; j < 8; j++) {
    int c = threadIdx.x + j*256;
    float v = (float)pa[c] + pb[c];
    x[j] = v; s += v; s2 += v*v;
  }
  #pragma unroll
  for (int off = 1; off < 64; off <<= 1) {
    s  += __shfl_xor(s,  off);
    s2 += __shfl_xor(s2, off);
  }
  const int wv = threadIdx.x >> 6;
  if ((threadIdx.x & 63) == 0) { red[wv] = s; red[4 + wv] = s2; }
  __syncthreads();
  s  = red[0] + red[1] + red[2] + red[3];
  s2 = red[4] + red[5] + red[6] + red[7];
  const float mu   = s * (1.0f / H_);
  const float var  = s2 * (1.0f / H_) - mu * mu;
  const float rstd = rsqrtf(var + 1e-12f);
  float* po = out + (size_t)row * H_;
  #pragma unroll
  for (int j = 0; j < 8; j++) {
    int c = threadIdx.x + j*256;
    po[c] = ((x[j] - mu) * rstd) * gamma[c] + beta[c];
  }
}

// ---------------------------------------------------------------------------
extern "C" void kernel_launch(void* const* d_in, const int* in_sizes, int n_in,
                              void* d_out, int out_size, void* d_ws, size_t ws_size,
                              hipStream_t stream)
{
  (void)in_sizes; (void)n_in; (void)out_size; (void)ws_size;
  const float* hidden = (const float*)d_in[0];
  const float* source = (const float*)d_in[1];
  const float* Wq = (const float*)d_in[2];
  const float* bq = (const float*)d_in[3];
  const float* Wk = (const float*)d_in[4];
  const float* bk = (const float*)d_in[5];
  const float* Wv = (const float*)d_in[6];
  const float* bv = (const float*)d_in[7];
  const float* Wd = (const float*)d_in[8];
  const float* bd = (const float*)d_in[9];
  const float* W1 = (const float*)d_in[10];
  const float* b1 = (const float*)d_in[11];
  const float* W2 = (const float*)d_in[12];
  const float* b2 = (const float*)d_in[13];
  const float* gamma = (const float*)d_in[14];
  const float* beta  = (const float*)d_in[15];

  // Workspace (100 MiB), liveness-audited (<=112 MiB proven in round 3):
  //   [0,16):  hb (t0-t1) -> Pb (t2-t3) -> O0 (t5-t6)
  //   [16,32): sb (t0-t1) -> O1 (t5-t6)
  //   [32,48): Qb (t1-t5) -> oFb (t7-t8)
  //   [48,56): Wqt (t0-t1) -> Ls (t5-t6)
  //   [56,64): W2t (t0-t2) -> ctx lo (t6-t7)
  //   [64,72): W1t (t0-t1) -> ctx hi
  //   [72,80): Wdt (t0-t7)
  //   [80,82): Wkt; [82,84): Wvt  (contiguous -> fused KV B-matrix)
  //   [84,100): Pl1 (t1-t2) -> KVb [84,92) (t3-t5) + Vtb [92,96) (t4-t5)
  char* ws = (char*)d_ws;
  const size_t M = 1048576;
  bf16*  rHB = (bf16*)(ws + 0*M);
  bf16*  rSB = (bf16*)(ws + 16*M);
  bf16*  Qb  = (bf16*)(ws + 32*M);
  bf16*  Wqt = (bf16*)(ws + 48*M);
  bf16*  W2t = (bf16*)(ws + 56*M);
  bf16*  W1t = (bf16*)(ws + 64*M);
  bf16*  Wdt = (bf16*)(ws + 72*M);
  bf16*  Wkt = (bf16*)(ws + 80*M);
  bf16*  Wvt = (bf16*)(ws + 82*M);
  bf16*  Pl1 = (bf16*)(ws + 84*M);
  bf16*  KVb = (bf16*)(ws + 84*M);
  bf16*  Vtb = (bf16*)(ws + 92*M);
  float* Ls  = (float*)(ws + 48*M);
  bf16*  Pb  = rHB;
  bf16*  O0  = rHB;
  bf16*  O1  = rSB;
  bf16*  ctx = (bf16*)(ws + 56*M);
  bf16*  oFb = Qb;

  // t0: everything input-independent in ONE launch
  prep<<<34816, 256, 0, stream>>>(Wq, W1, W2, Wd, Wk, Wv, hidden, source,
                                  Wqt, W1t, W2t, Wdt, Wkt, Wvt, rHB, rSB);
  // t1: fused Q-proj (pre-scaled by QSCALE) + lin1(relu)
  gemm_dual<<<dim3(16,32,2), 256, 0, stream>>>(
      rHB, Wqt, bq, Qb,  0, QSCALE,
      rSB, W1t, b1, Pl1, 1, 1.0f, 2048, 2048);
  // t2: lin2 with +Pl1 residual -> Pb
  gemm_one<<<dim3(16,32), 256, 0, stream>>>(Pl1, W2t, b2, b2, 1<<30, Pl1,
                                            Pb, 2048, 2048, 0, 1.0f);
  // t3: fused K|V projection (bias split in epilogue; Wkt|Wvt contiguous)
  gemm_one<<<dim3(8,32), 256, 0, stream>>>(Pb, Wkt, bk, bv, 512, nullptr,
                                           KVb, 1024, 2048, 0, 1.0f);
  // t4
  transpose_v<<<dim3(64,4,8), 256, 0, stream>>>(KVb, Vtb);
  // t5: attention partials
  attn_partial<<<dim3(16,16,4), 256, 0, stream>>>(Qb, KVb, Vtb, O0, Ls);
  // t6: combine -> ctx
  attn_combine<<<4096, 256, 0, stream>>>(O0, O1, Ls, Ls + B_*NH_*S_, ctx);
  // t7: out proj
  gemm_one<<<dim3(16,32), 256, 0, stream>>>(ctx, Wdt, bd, bd, 1<<30, nullptr,
                                            oFb, 2048, 2048, 0, 1.0f);
  // t8
  ln_fused<<<4096, 256, 0, stream>>>(oFb, hidden, gamma, beta, (float*)d_out);
}

// Round 3
// 599.108 us; speedup vs baseline: 1.0723x; 1.0723x over previous
//
#include <hip/hip_runtime.h>
#include <hip/hip_bf16.h>

typedef __bf16 bf16;
typedef __bf16 bf16x2 __attribute__((ext_vector_type(2)));
typedef __bf16 bf16x4 __attribute__((ext_vector_type(4)));
typedef __bf16 bf16x8 __attribute__((ext_vector_type(8)));
typedef float  f32x4  __attribute__((ext_vector_type(4)));
typedef unsigned int u32x4 __attribute__((ext_vector_type(4)));

#define H_   2048
#define S_   2048
#define B_   2
#define NH_  16
#define NKV_ 4
#define HD_  128
#define KVS  1024   /* fused K|V row width */

// 1/sqrt(HD) * log2(e): folded into Q so attention can use exp2 directly
#define QSCALE 0.12751743f

__device__ __forceinline__ f32x4 mfma16(bf16x8 a, bf16x8 b, f32x4 c) {
  return __builtin_amdgcn_mfma_f32_16x16x32_bf16(a, b, c, 0, 0, 0);
}

// async global->LDS, 16B per lane (m97 pattern; LDS dst lane-contiguous)
typedef __attribute__((address_space(3))) unsigned int lds_u32_t;
typedef const __attribute__((address_space(1))) unsigned int glb_u32_t;
__device__ __forceinline__ void glds16(const bf16* g, bf16* l) {
  __builtin_amdgcn_global_load_lds((glb_u32_t*)g, (lds_u32_t*)l, 16, 0, 0);
}

// pack two f32 -> one dword of 2 bf16 (lo = first arg)
__device__ __forceinline__ unsigned pk2(float a, float b) {
  bf16x2 v = { (bf16)a, (bf16)b };
  return __builtin_bit_cast(unsigned, v);
}

// ---------------------------------------------------------------------------
// PREP mega-kernel: both activation converts + all six weight transposes in
// ONE launch (they are mutually independent, inputs-only). 1-D grid, ranges:
//   [0,8192)      hidden -> hb   (fp32->bf16, 1024 elems/block)
//   [8192,16384)  source -> sb
//   [16384,+4096) Wq^T  [+4096) W1^T  [+4096) W2^T  [+4096) Wd^T
//   [+1024) Wk^T  [+1024) Wv^T
// ---------------------------------------------------------------------------
__global__ __launch_bounds__(256)
void prep(const float* __restrict__ Wq, const float* __restrict__ W1,
          const float* __restrict__ W2, const float* __restrict__ Wd,
          const float* __restrict__ Wk, const float* __restrict__ Wv,
          const float* __restrict__ hidden, const float* __restrict__ source,
          bf16* __restrict__ Wqt, bf16* __restrict__ W1t,
          bf16* __restrict__ W2t, bf16* __restrict__ Wdt,
          bf16* __restrict__ Wkt, bf16* __restrict__ Wvt,
          bf16* __restrict__ hb,  bf16* __restrict__ sb)
{
  __shared__ bf16 t[32][33];
  int idx = blockIdx.x;
  if (idx < 16384) {                       // activation converts
    const float* in = (idx < 8192) ? hidden : source;
    bf16*       out = (idx < 8192) ? hb : sb;
    const int i = idx & 8191;
    const size_t off = ((size_t)i * 256 + threadIdx.x) * 4;
    const float4 v = *(const float4*)(in + off);
    bf16x4 o = { (bf16)v.x, (bf16)v.y, (bf16)v.z, (bf16)v.w };
    *(bf16x4*)(out + off) = o;
    return;
  }
  idx -= 16384;
  const float* in; bf16* out; int N;
  if      (idx < 4096)  { in = Wq; out = Wqt; N = 2048; }
  else if (idx < 8192)  { in = W1; out = W1t; N = 2048; idx -= 4096; }
  else if (idx < 12288) { in = W2; out = W2t; N = 2048; idx -= 8192; }
  else if (idx < 16384) { in = Wd; out = Wdt; N = 2048; idx -= 12288; }
  else if (idx < 17408) { in = Wk; out = Wkt; N = 512;  idx -= 16384; }
  else                  { in = Wv; out = Wvt; N = 512;  idx -= 17408; }
  const int K = 2048;
  const int tx = threadIdx.x & 31, ty = threadIdx.x >> 5;
  const int k0 = (idx & 63) * 32, n0 = (idx >> 6) * 32;
  #pragma unroll
  for (int i = 0; i < 4; i++)
    t[ty + i*8][tx] = (bf16)in[(size_t)(k0 + ty + i*8) * N + n0 + tx];
  __syncthreads();
  #pragma unroll
  for (int i = 0; i < 4; i++)
    out[(size_t)(n0 + ty + i*8) * K + k0 + tx] = t[tx][ty + i*8];
}

// ---------------------------------------------------------------------------
// V half of fused KV [b, s, 1024] -> Vt [b, kv, d, s]
// ---------------------------------------------------------------------------
__global__ __launch_bounds__(256)
void transpose_v(const bf16* __restrict__ KVin, bf16* __restrict__ Vt)
{
  __shared__ bf16 t[32][33];
  const int tx = threadIdx.x & 31, ty = threadIdx.x >> 5;
  const int s0 = blockIdx.x * 32, d0 = blockIdx.y * 32;
  const int bk = blockIdx.z;
  const int b = bk >> 2, kv = bk & 3;
  const bf16* src = KVin + (size_t)b * S_ * KVS + 512 + kv * HD_;
  #pragma unroll
  for (int i = 0; i < 4; i++)
    t[ty + i*8][tx] = src[(size_t)(s0 + ty + i*8) * KVS + d0 + tx];
  __syncthreads();
  bf16* dst = Vt + (size_t)bk * HD_ * S_;
  #pragma unroll
  for (int i = 0; i < 4; i++)
    dst[(size_t)(d0 + ty + i*8) * S_ + s0 + tx] = t[tx][ty + i*8];
}

// ---------------------------------------------------------------------------
// 128x128-tile bf16 MFMA GEMM body, double-buffered glds16 staging.
// bias split: col < nsplit -> bias[col], else bias2[col-nsplit] (fused KV).
// ---------------------------------------------------------------------------
__device__ __forceinline__
void gemm_body(const bf16* __restrict__ A, const bf16* __restrict__ Wt,
               const float* __restrict__ bias, const float* __restrict__ bias2,
               int nsplit, const bf16* __restrict__ resid,
               bf16* __restrict__ outB, int N, int K, int relu, float oscale,
               int m0, int n0, bf16* As, bf16* Bs)
{
  const int tid  = threadIdx.x;
  const int lane = tid & 63;
  const int w    = tid >> 6;
  const int wm = w & 1, wn = w >> 1;
  const int quad = lane >> 4, l16 = lane & 15;
  const int g_r = lane >> 2;
  const int g_c = (lane & 3) * 8;

  const f32x4 fz = {0.f, 0.f, 0.f, 0.f};
  f32x4 acc[4][4];
  #pragma unroll
  for (int i = 0; i < 4; i++)
    #pragma unroll
    for (int j = 0; j < 4; j++) acc[i][j] = fz;

  auto stage = [&](int nb, int k0) {
    #pragma unroll
    for (int i = 0; i < 2; i++) {
      const int rb = (w*2 + i) * 16;
      glds16(A  + (size_t)(m0 + rb + g_r) * K + k0 + g_c, As + nb*4096 + rb*32 + lane*8);
      glds16(Wt + (size_t)(n0 + rb + g_r) * K + k0 + g_c, Bs + nb*4096 + rb*32 + lane*8);
    }
  };

  stage(0, 0);
  const int NK = K >> 5;
  for (int it = 0; it < NK; it++) {
    const int bf = it & 1;
    __syncthreads();
    if (it + 1 < NK) stage(bf ^ 1, (it + 1) << 5);
    bf16x8 af[4], bfr[4];
    #pragma unroll
    for (int i = 0; i < 4; i++)
      af[i]  = *(const bf16x8*)(As + bf*4096 + (wm*64 + i*16 + l16)*32 + quad*8);
    #pragma unroll
    for (int j = 0; j < 4; j++)
      bfr[j] = *(const bf16x8*)(Bs + bf*4096 + (wn*64 + j*16 + l16)*32 + quad*8);
    #pragma unroll
    for (int i = 0; i < 4; i++)
      #pragma unroll
      for (int j = 0; j < 4; j++)
        acc[i][j] = mfma16(af[i], bfr[j], acc[i][j]);
  }

  // C/D layout: col = lane&15, row = (lane>>4)*4 + reg   [m89/m91]
  #pragma unroll
  for (int i = 0; i < 4; i++) {
    const int row = m0 + wm*64 + i*16 + quad*4;
    #pragma unroll
    for (int j = 0; j < 4; j++) {
      const int col = n0 + wn*64 + j*16 + l16;
      const float bi = (col < nsplit) ? bias[col] : bias2[col - nsplit];
      #pragma unroll
      for (int r = 0; r < 4; r++) {
        float v = acc[i][j][r] + bi;
        if (relu) v = fmaxf(v, 0.f);
        v *= oscale;
        size_t idx = (size_t)(row + r) * N + col;
        if (resid) v += (float)resid[idx];
        outB[idx] = (bf16)v;
      }
    }
  }
}

__global__ __launch_bounds__(256)
void gemm_one(const bf16* __restrict__ A, const bf16* __restrict__ Wt,
              const float* __restrict__ bias, const float* __restrict__ bias2,
              int nsplit, const bf16* __restrict__ resid,
              bf16* __restrict__ outB, int N, int K, int relu, float oscale)
{
  __shared__ __align__(16) bf16 As[2*128*32];
  __shared__ __align__(16) bf16 Bs[2*128*32];
  gemm_body(A, Wt, bias, bias2, nsplit, resid, outB, N, K, relu, oscale,
            blockIdx.y*128, blockIdx.x*128, As, Bs);
}

// Two independent GEMMs in one launch (z selects): Q-proj and lin1.
__global__ __launch_bounds__(256)
void gemm_dual(const bf16* __restrict__ A0, const bf16* __restrict__ W0,
               const float* __restrict__ b0, bf16* __restrict__ o0,
               int relu0, float s0,
               const bf16* __restrict__ A1, const bf16* __restrict__ W1,
               const float* __restrict__ b1, bf16* __restrict__ o1,
               int relu1, float s1, int N, int K)
{
  __shared__ __align__(16) bf16 As[2*128*32];
  __shared__ __align__(16) bf16 Bs[2*128*32];
  if (blockIdx.z == 0)
    gemm_body(A0, W0, b0, b0, 1<<30, nullptr, o0, N, K, relu0, s0,
              blockIdx.y*128, blockIdx.x*128, As, Bs);
  else
    gemm_body(A1, W1, b1, b1, 1<<30, nullptr, o1, N, K, relu1, s1,
              blockIdx.y*128, blockIdx.x*128, As, Bs);
}

// ---------------------------------------------------------------------------
// GQA attention PARTIAL, round-11: round-10 structure, but NO min-waves cap.
// Round-10 lesson: __launch_bounds__(256,4) forced VGPR=64 < ~130 live regs
// -> in-loop scratch spills -> 250 MB/dispatch of HBM spill traffic (FETCH
// 41->261 MB) -> 175 us. Plain (256) lets the allocator keep all state in
// regs (~130-160 VGPR, 3 blocks/CU via VGPR; LDS 32KB allows 5).
//  * swapped QK^T (mfma(K,Q)) -> P lands q=lane&15, s in regs.
//  * PV A-fragment built IN-REGISTER via pull-model __shfl transpose.
//  * K/V staged FRAGMENT-MAJOR: every ds_read_b128 is base+lane*16,
//    conflict-free.
//  * s_setprio(1) around both MFMA clusters (T5).
// Grid (16 qt, 16 h, B*2 s-halves) = 1024 blocks.
// ---------------------------------------------------------------------------
__global__ __launch_bounds__(256)
void attn_partial(const bf16* __restrict__ Q, const bf16* __restrict__ KV,
                  const bf16* __restrict__ Vt, bf16* __restrict__ OpBase,
                  float* __restrict__ LsBase)
{
  // Ks: [buf][kt*2+half][lane][8]  (chunk = one 16s x 32d K fragment, 1KB)
  // Vs: [buf][nt]       [lane][8]  (chunk = one 16d x 32s V^T fragment)
  __shared__ __align__(16) bf16 Ks[2*4096];
  __shared__ __align__(16) bf16 Vs[2*4096];
  const int tid = threadIdx.x;
  const int lane = tid & 63, w = tid >> 6;
  const int quad = lane >> 4, l16 = lane & 15;
  const int qt = blockIdx.x, h = blockIdx.y;
  const int b = blockIdx.z >> 1, sh = blockIdx.z & 1;
  const int kv = h >> 2;                 // G = 4
  const int qbase = qt * 128 + w * 32;
  const int s_begin = sh * (S_/2);

  bf16*  Op = OpBase + (size_t)sh * 8388608;        // +16 MiB half stride
  float* Lp = LsBase + (size_t)sh * (B_*NH_*S_);

  const bf16* Qp = Q  + ((size_t)b * S_ + qbase) * H_ + h * HD_;
  const bf16* Kp = KV + (size_t)b * S_ * KVS + kv * HD_;
  const bf16* Vp = Vt + (size_t)(b * NKV_ + kv) * HD_ * S_;

  // fragment-row / fragment-col for pre-permuted staging source
  const int fr = lane & 15;
  const int fc = (lane >> 4) * 8;

  const f32x4 fz = {0.f, 0.f, 0.f, 0.f};

  bf16x8 qf[2][4];
  #pragma unroll
  for (int i = 0; i < 2; i++)
    #pragma unroll
    for (int kt = 0; kt < 4; kt++)
      qf[i][kt] = *(const bf16x8*)(Qp + (size_t)(i*16 + l16) * H_ + kt*32 + quad*8);

  f32x4 o[2][8];
  #pragma unroll
  for (int i = 0; i < 2; i++)
    #pragma unroll
    for (int n = 0; n < 8; n++) o[i][n] = fz;
  float lsum[2] = {0.f, 0.f};

  // wave w stages K fragments (kt=w, halves 0/1) and V fragments (nt=w, 4+w)
  auto stageKV = [&](int nb, int s0) {
    bf16* Kb = Ks + nb*4096;
    bf16* Vb = Vs + nb*4096;
    glds16(Kp + (size_t)(s0 +      fr) * KVS + w*32 + fc, Kb + (w*2+0)*512 + lane*8);
    glds16(Kp + (size_t)(s0 + 16 + fr) * KVS + w*32 + fc, Kb + (w*2+1)*512 + lane*8);
    glds16(Vp + (size_t)(w*16     + fr) * S_ + s0 + fc,   Vb + w*512       + lane*8);
    glds16(Vp + (size_t)((4+w)*16 + fr) * S_ + s0 + fc,   Vb + (4+w)*512   + lane*8);
  };

  stageKV(0, s_begin);

  const int NIT = (S_/2) / 32;   // 32
  for (int it = 0; it < NIT; it++) {
    const int bf = it & 1;
    __syncthreads();
    if (it + 1 < NIT) stageKV(bf ^ 1, s_begin + (it + 1) * 32);

    // ---- QK^T, swapped operands: sa[i][half] has q=l16, s=half*16+quad*4+r
    const bf16* Kb = Ks + bf*4096;
    f32x4 sa[2][2];
    sa[0][0] = fz; sa[0][1] = fz; sa[1][0] = fz; sa[1][1] = fz;
    __builtin_amdgcn_s_setprio(1);
    #pragma unroll
    for (int kt = 0; kt < 4; kt++) {
      bf16x8 kf0 = *(const bf16x8*)(Kb + (kt*2+0)*512 + lane*8);
      bf16x8 kf1 = *(const bf16x8*)(Kb + (kt*2+1)*512 + lane*8);
      #pragma unroll
      for (int i = 0; i < 2; i++) {
        sa[i][0] = mfma16(kf0, qf[i][kt], sa[i][0]);
        sa[i][1] = mfma16(kf1, qf[i][kt], sa[i][1]);
      }
    }
    __builtin_amdgcn_s_setprio(0);

    // ---- softmax numerator + in-register transpose to PV A-fragments
    bf16x8 pf[2];
    #pragma unroll
    for (int i = 0; i < 2; i++) {
      float p[2][4];
      #pragma unroll
      for (int nt = 0; nt < 2; nt++)
        #pragma unroll
        for (int r = 0; r < 4; r++) {
          p[nt][r] = exp2f(sa[i][nt][r]);   // Q pre-scaled by 1/sqrt(d)*log2e
          lsum[i] += p[nt][r];
        }
      // source: lane (q=l16, quad') holds s = quad'*4+r (nt0), 16+quad'*4+r (nt1)
      unsigned Apk = pk2(p[0][0], p[0][1]);   // s = q'*4 + {0,1}
      unsigned Bpk = pk2(p[0][2], p[0][3]);   // s = q'*4 + {2,3}
      unsigned Cpk = pk2(p[1][0], p[1][1]);   // s = 16 + q'*4 + {0,1}
      unsigned Dpk = pk2(p[1][2], p[1][3]);   // s = 16 + q'*4 + {2,3}
      // target: lane (q=l16, quad) needs s = quad*8 + 0..7 as 4 dwords.
      //   quad0: A,B from q'0 then q'1 | quad1: A,B from q'2 then q'3
      //   quad2: C,D from q'0 then q'1 | quad3: C,D from q'2 then q'3
      const int srcL = l16 + ((quad & 1) << 5);   // lane of quad' = 2*(quad&1)
      const bool hi = (quad >= 2);
      const unsigned a0 = __shfl(Apk, srcL),      b0 = __shfl(Bpk, srcL);
      const unsigned a1 = __shfl(Apk, srcL + 16), b1 = __shfl(Bpk, srcL + 16);
      const unsigned c0 = __shfl(Cpk, srcL),      d0 = __shfl(Dpk, srcL);
      const unsigned c1 = __shfl(Cpk, srcL + 16), d1 = __shfl(Dpk, srcL + 16);
      u32x4 t;
      t.x = hi ? c0 : a0;
      t.y = hi ? d0 : b0;
      t.z = hi ? c1 : a1;
      t.w = hi ? d1 : b1;
      pf[i] = __builtin_bit_cast(bf16x8, t);
    }

    // ---- PV
    const bf16* Vb = Vs + bf*4096;
    __builtin_amdgcn_s_setprio(1);
    #pragma unroll
    for (int nt = 0; nt < 8; nt++) {
      bf16x8 vf = *(const bf16x8*)(Vb + nt*512 + lane*8);
      o[0][nt] = mfma16(pf[0], vf, o[0][nt]);
      o[1][nt] = mfma16(pf[1], vf, o[1][nt]);
    }
    __builtin_amdgcn_s_setprio(0);
  }

  bf16* op = Op + ((size_t)b * S_ + qbase) * H_ + h * HD_;
  #pragma unroll
  for (int i = 0; i < 2; i++)
    #pragma unroll
    for (int nt = 0; nt < 8; nt++)
      #pragma unroll
      for (int r = 0; r < 4; r++)
        op[(size_t)(i*16 + quad*4 + r) * H_ + nt*16 + l16] = (bf16)o[i][nt][r];

  // row-sums: lane holds partial over its 8 s-values; reduce across quads
  float* lp = Lp + (size_t)(b * NH_ + h) * S_ + qbase;
  #pragma unroll
  for (int i = 0; i < 2; i++) {
    float s = lsum[i];
    s += __shfl_xor(s, 16);
    s += __shfl_xor(s, 32);
    if (lane < 16) lp[i*16 + lane] = s;
  }
}

// ---------------------------------------------------------------------------
// ctx = (O0+O1)/(L0+L1); one block per (b,s) row.
// ---------------------------------------------------------------------------
__global__ __launch_bounds__(256)
void attn_combine(const bf16* __restrict__ O0, const bf16* __restrict__ O1,
                  const float* __restrict__ L0, const float* __restrict__ L1,
                  bf16* __restrict__ ctx)
{
  const int row = blockIdx.x;              // b*S + s
  const int b = row >> 11, s = row & 2047;
  const int tid = threadIdx.x;
  const int h = tid >> 4;
  const size_t idx = (size_t)row * H_ + tid * 8;
  const size_t li  = (size_t)(b * NH_ + h) * S_ + s;
  const float rinv = 1.f / (L0[li] + L1[li]);
  bf16x8 a = *(const bf16x8*)(O0 + idx);
  bf16x8 c = *(const bf16x8*)(O1 + idx);
  bf16x8 o;
  #pragma unroll
  for (int k = 0; k < 8; k++)
    o[k] = (bf16)(((float)a[k] + (float)c[k]) * rinv);
  *(bf16x8*)(ctx + idx) = o;
}

// ---------------------------------------------------------------------------
// y = LN(a + hidden)*gamma + beta. fp32 out.
// ---------------------------------------------------------------------------
__global__ __launch_bounds__(256)
void ln_fused(const bf16* __restrict__ a, const float* __restrict__ hidden,
              const float* __restrict__ gamma, const float* __restrict__ beta,
              float* __restrict__ out)
{
  __shared__ float red[8];
  const int row = blockIdx.x;
  const bf16*  pa = a      + (size_t)row * H_;
  const float* pb = hidden + (size_t)row * H_;
  float x[8]; float s = 0.f, s2 = 0.f;
  #pragma unroll
  for (int j = 0; j < 8; j++) {
    int c = threadIdx.x + j*256;
    float v = (float)pa[c] + pb[c];
    x[j] = v; s += v; s2 += v*v;
  }
  #pragma unroll
  for (int off = 1; off < 64; off <<= 1) {
    s  += __shfl_xor(s,  off);
    s2 += __shfl_xor(s2, off);
  }
  const int wv = threadIdx.x >> 6;
  if ((threadIdx.x & 63) == 0) { red[wv] = s; red[4 + wv] = s2; }
  __syncthreads();
  s  = red[0] + red[1] + red[2] + red[3];
  s2 = red[4] + red[5] + red[6] + red[7];
  const float mu   = s * (1.0f / H_);
  const float var  = s2 * (1.0f / H_) - mu * mu;
  const float rstd = rsqrtf(var + 1e-12f);
  float* po = out + (size_t)row * H_;
  #pragma unroll
  for (int j = 0; j < 8; j++) {
    int c = threadIdx.x + j*256;
    po[c] = ((x[j] - mu) * rstd) * gamma[c] + beta[c];
  }
}

// ---------------------------------------------------------------------------
extern "C" void kernel_launch(void* const* d_in, const int* in_sizes, int n_in,
                              void* d_out, int out_size, void* d_ws, size_t ws_size,
                              hipStream_t stream)
{
  (void)in_sizes; (void)n_in; (void)out_size; (void)ws_size;
  const float* hidden = (const float*)d_in[0];
  const float* source = (const float*)d_in[1];
  const float* Wq = (const float*)d_in[2];
  const float* bq = (const float*)d_in[3];
  const float* Wk = (const float*)d_in[4];
  const float* bk = (const float*)d_in[5];
  const float* Wv = (const float*)d_in[6];
  const float* bv = (const float*)d_in[7];
  const float* Wd = (const float*)d_in[8];
  const float* bd = (const float*)d_in[9];
  const float* W1 = (const float*)d_in[10];
  const float* b1 = (const float*)d_in[11];
  const float* W2 = (const float*)d_in[12];
  const float* b2 = (const float*)d_in[13];
  const float* gamma = (const float*)d_in[14];
  const float* beta  = (const float*)d_in[15];

  // Workspace (100 MiB), liveness-audited (<=112 MiB proven in round 3):
  //   [0,16):  hb (t0-t1) -> Pb (t2-t3) -> O0 (t5-t6)
  //   [16,32): sb (t0-t1) -> O1 (t5-t6)
  //   [32,48): Qb (t1-t5) -> oFb (t7-t8)
  //   [48,56): Wqt (t0-t1) -> Ls (t5-t6)
  //   [56,64): W2t (t0-t2) -> ctx lo (t6-t7)
  //   [64,72): W1t (t0-t1) -> ctx hi
  //   [72,80): Wdt (t0-t7)
  //   [80,82): Wkt; [82,84): Wvt  (contiguous -> fused KV B-matrix)
  //   [84,100): Pl1 (t1-t2) -> KVb [84,92) (t3-t5) + Vtb [92,96) (t4-t5)
  char* ws = (char*)d_ws;
  const size_t M = 1048576;
  bf16*  rHB = (bf16*)(ws + 0*M);
  bf16*  rSB = (bf16*)(ws + 16*M);
  bf16*  Qb  = (bf16*)(ws + 32*M);
  bf16*  Wqt = (bf16*)(ws + 48*M);
  bf16*  W2t = (bf16*)(ws + 56*M);
  bf16*  W1t = (bf16*)(ws + 64*M);
  bf16*  Wdt = (bf16*)(ws + 72*M);
  bf16*  Wkt = (bf16*)(ws + 80*M);
  bf16*  Wvt = (bf16*)(ws + 82*M);
  bf16*  Pl1 = (bf16*)(ws + 84*M);
  bf16*  KVb = (bf16*)(ws + 84*M);
  bf16*  Vtb = (bf16*)(ws + 92*M);
  float* Ls  = (float*)(ws + 48*M);
  bf16*  Pb  = rHB;
  bf16*  O0  = rHB;
  bf16*  O1  = rSB;
  bf16*  ctx = (bf16*)(ws + 56*M);
  bf16*  oFb = Qb;

  // t0: everything input-independent in ONE launch
  prep<<<34816, 256, 0, stream>>>(Wq, W1, W2, Wd, Wk, Wv, hidden, source,
                                  Wqt, W1t, W2t, Wdt, Wkt, Wvt, rHB, rSB);
  // t1: fused Q-proj (pre-scaled by QSCALE) + lin1(relu)
  gemm_dual<<<dim3(16,32,2), 256, 0, stream>>>(
      rHB, Wqt, bq, Qb,  0, QSCALE,
      rSB, W1t, b1, Pl1, 1, 1.0f, 2048, 2048);
  // t2: lin2 with +Pl1 residual -> Pb
  gemm_one<<<dim3(16,32), 256, 0, stream>>>(Pl1, W2t, b2, b2, 1<<30, Pl1,
                                            Pb, 2048, 2048, 0, 1.0f);
  // t3: fused K|V projection (bias split in epilogue; Wkt|Wvt contiguous)
  gemm_one<<<dim3(8,32), 256, 0, stream>>>(Pb, Wkt, bk, bv, 512, nullptr,
                                           KVb, 1024, 2048, 0, 1.0f);
  // t4
  transpose_v<<<dim3(64,4,8), 256, 0, stream>>>(KVb, Vtb);
  // t5: attention partials
  attn_partial<<<dim3(16,16,4), 256, 0, stream>>>(Qb, KVb, Vtb, O0, Ls);
  // t6: combine -> ctx
  attn_combine<<<4096, 256, 0, stream>>>(O0, O1, Ls, Ls + B_*NH_*S_, ctx);
  // t7: out proj
  gemm_one<<<dim3(16,32), 256, 0, stream>>>(ctx, Wdt, bd, bd, 1<<30, nullptr,
                                            oFb, 2048, 2048, 0, 1.0f);
  // t8
  ln_fused<<<4096, 256, 0, stream>>>(oFb, hidden, gamma, beta, (float*)d_out);
}

// Round 4
// 597.371 us; speedup vs baseline: 1.0754x; 1.0029x over previous
//
#include <hip/hip_runtime.h>
#include <hip/hip_bf16.h>

typedef __bf16 bf16;
typedef __bf16 bf16x2 __attribute__((ext_vector_type(2)));
typedef __bf16 bf16x4 __attribute__((ext_vector_type(4)));
typedef __bf16 bf16x8 __attribute__((ext_vector_type(8)));
typedef float  f32x4  __attribute__((ext_vector_type(4)));
typedef unsigned int u32x4 __attribute__((ext_vector_type(4)));

#define H_   2048
#define S_   2048
#define B_   2
#define NH_  16
#define NKV_ 4
#define HD_  128
#define KVS  1024   /* fused K|V projection row width */

// 1/sqrt(HD) * log2(e): folded into Q so attention can use exp2 directly
#define QSCALE 0.12751743f

__device__ __forceinline__ f32x4 mfma16(bf16x8 a, bf16x8 b, f32x4 c) {
  return __builtin_amdgcn_mfma_f32_16x16x32_bf16(a, b, c, 0, 0, 0);
}

// async global->LDS, 16B per lane (m97 pattern; LDS dst lane-contiguous)
typedef __attribute__((address_space(3))) unsigned int lds_u32_t;
typedef const __attribute__((address_space(1))) unsigned int glb_u32_t;
__device__ __forceinline__ void glds16(const bf16* g, bf16* l) {
  __builtin_amdgcn_global_load_lds((glb_u32_t*)g, (lds_u32_t*)l, 16, 0, 0);
}

// pack two f32 -> one dword of 2 bf16 (lo = first arg)
__device__ __forceinline__ unsigned pk2(float a, float b) {
  bf16x2 v = { (bf16)a, (bf16)b };
  return __builtin_bit_cast(unsigned, v);
}

// ---------------------------------------------------------------------------
// Fragment-major layouts (tile = 32 rows of s|q x 128 d = 4096 bf16 = 8KB,
// 8 chunks x 512 elems; chunk byte range is CONTIGUOUS 1KB = 64 lanes x 16B):
//  K/Q tile elem (r in 0..31, d in 0..127):
//    chunk = (d>>5)*2 + ((r>>4)&1); lane = ((d>>3)&3)*16 + (r&15); e = d&7
//  V tile elem (s in 0..31, d in 0..127)  [V^T fragments for PV]:
//    chunk = d>>4;  lane = ((s&31)>>3)*16 + (d&15);  e = s&7
// Tile index: K/V: ((b*4+kv)*64 + (s>>5));  Q: ((b*16+h)*64 + (q>>5)).
// ---------------------------------------------------------------------------

// ---------------------------------------------------------------------------
// PREP mega-kernel: both activation converts + all six weight transposes in
// ONE launch (they are mutually independent, inputs-only). 1-D grid, ranges:
//   [0,8192)      hidden -> hb   (fp32->bf16, 1024 elems/block)
//   [8192,16384)  source -> sb
//   [16384,+4096) Wq^T  [+4096) W1^T  [+4096) W2^T  [+4096) Wd^T
//   [+1024) Wk^T  [+1024) Wv^T
// ---------------------------------------------------------------------------
__global__ __launch_bounds__(256)
void prep(const float* __restrict__ Wq, const float* __restrict__ W1,
          const float* __restrict__ W2, const float* __restrict__ Wd,
          const float* __restrict__ Wk, const float* __restrict__ Wv,
          const float* __restrict__ hidden, const float* __restrict__ source,
          bf16* __restrict__ Wqt, bf16* __restrict__ W1t,
          bf16* __restrict__ W2t, bf16* __restrict__ Wdt,
          bf16* __restrict__ Wkt, bf16* __restrict__ Wvt,
          bf16* __restrict__ hb,  bf16* __restrict__ sb)
{
  __shared__ bf16 t[32][33];
  int idx = blockIdx.x;
  if (idx < 16384) {                       // activation converts
    const float* in = (idx < 8192) ? hidden : source;
    bf16*       out = (idx < 8192) ? hb : sb;
    const int i = idx & 8191;
    const size_t off = ((size_t)i * 256 + threadIdx.x) * 4;
    const float4 v = *(const float4*)(in + off);
    bf16x4 o = { (bf16)v.x, (bf16)v.y, (bf16)v.z, (bf16)v.w };
    *(bf16x4*)(out + off) = o;
    return;
  }
  idx -= 16384;
  const float* in; bf16* out; int N;
  if      (idx < 4096)  { in = Wq; out = Wqt; N = 2048; }
  else if (idx < 8192)  { in = W1; out = W1t; N = 2048; idx -= 4096; }
  else if (idx < 12288) { in = W2; out = W2t; N = 2048; idx -= 8192; }
  else if (idx < 16384) { in = Wd; out = Wdt; N = 2048; idx -= 12288; }
  else if (idx < 17408) { in = Wk; out = Wkt; N = 512;  idx -= 16384; }
  else                  { in = Wv; out = Wvt; N = 512;  idx -= 17408; }
  const int K = 2048;
  const int tx = threadIdx.x & 31, ty = threadIdx.x >> 5;
  const int k0 = (idx & 63) * 32, n0 = (idx >> 6) * 32;
  #pragma unroll
  for (int i = 0; i < 4; i++)
    t[ty + i*8][tx] = (bf16)in[(size_t)(k0 + ty + i*8) * N + n0 + tx];
  __syncthreads();
  #pragma unroll
  for (int i = 0; i < 4; i++)
    out[(size_t)(n0 + ty + i*8) * K + k0 + tx] = t[tx][ty + i*8];
}

// ---------------------------------------------------------------------------
// 128x128-tile bf16 MFMA GEMM body, double-buffered glds16 staging.
// bias split: col < nsplit -> bias[col], else bias2[col-nsplit] (fused KV).
// mode: 0 = row-major store; 1 = KV fragment-major (outB=KF, outC=VF);
//       2 = Q fragment-major (outB=QF).
// ---------------------------------------------------------------------------
__device__ __forceinline__
void gemm_body(const bf16* __restrict__ A, const bf16* __restrict__ Wt,
               const float* __restrict__ bias, const float* __restrict__ bias2,
               int nsplit, const bf16* __restrict__ resid,
               bf16* __restrict__ outB, bf16* __restrict__ outC,
               int N, int K, int relu, float oscale, int mode,
               int m0, int n0, bf16* As, bf16* Bs)
{
  const int tid  = threadIdx.x;
  const int lane = tid & 63;
  const int w    = tid >> 6;
  const int wm = w & 1, wn = w >> 1;
  const int quad = lane >> 4, l16 = lane & 15;
  const int g_r = lane >> 2;
  const int g_c = (lane & 3) * 8;

  const f32x4 fz = {0.f, 0.f, 0.f, 0.f};
  f32x4 acc[4][4];
  #pragma unroll
  for (int i = 0; i < 4; i++)
    #pragma unroll
    for (int j = 0; j < 4; j++) acc[i][j] = fz;

  auto stage = [&](int nb, int k0) {
    #pragma unroll
    for (int i = 0; i < 2; i++) {
      const int rb = (w*2 + i) * 16;
      glds16(A  + (size_t)(m0 + rb + g_r) * K + k0 + g_c, As + nb*4096 + rb*32 + lane*8);
      glds16(Wt + (size_t)(n0 + rb + g_r) * K + k0 + g_c, Bs + nb*4096 + rb*32 + lane*8);
    }
  };

  stage(0, 0);
  const int NK = K >> 5;
  for (int it = 0; it < NK; it++) {
    const int bf = it & 1;
    __syncthreads();
    if (it + 1 < NK) stage(bf ^ 1, (it + 1) << 5);
    bf16x8 af[4], bfr[4];
    #pragma unroll
    for (int i = 0; i < 4; i++)
      af[i]  = *(const bf16x8*)(As + bf*4096 + (wm*64 + i*16 + l16)*32 + quad*8);
    #pragma unroll
    for (int j = 0; j < 4; j++)
      bfr[j] = *(const bf16x8*)(Bs + bf*4096 + (wn*64 + j*16 + l16)*32 + quad*8);
    #pragma unroll
    for (int i = 0; i < 4; i++)
      #pragma unroll
      for (int j = 0; j < 4; j++)
        acc[i][j] = mfma16(af[i], bfr[j], acc[i][j]);
  }

  // C/D layout: col = lane&15, row = (lane>>4)*4 + reg   [m89/m91]
  #pragma unroll
  for (int i = 0; i < 4; i++) {
    const int row = m0 + wm*64 + i*16 + quad*4;
    #pragma unroll
    for (int j = 0; j < 4; j++) {
      const int col = n0 + wn*64 + j*16 + l16;
      const float bi = (col < nsplit) ? bias[col] : bias2[col - nsplit];
      #pragma unroll
      for (int r = 0; r < 4; r++) {
        float v = acc[i][j][r] + bi;
        if (relu) v = fmaxf(v, 0.f);
        v *= oscale;
        const int rowg = row + r;
        if (mode == 0) {
          size_t idx = (size_t)rowg * N + col;
          if (resid) v += (float)resid[idx];
          outB[idx] = (bf16)v;
        } else if (mode == 1) {            // K|V fragment-major
          const int bb = rowg >> 11, s = rowg & 2047;
          if (col < 512) {
            const int kvq = col >> 7, d = col & 127;
            size_t off = ((size_t)((bb*4 + kvq)*64 + (s >> 5))) * 4096
                       + ((d >> 5)*2 + ((s >> 4) & 1)) * 512
                       + (((d >> 3) & 3)*16 + (s & 15)) * 8 + (d & 7);
            outB[off] = (bf16)v;
          } else {
            const int kvq = (col - 512) >> 7, d = (col - 512) & 127;
            size_t off = ((size_t)((bb*4 + kvq)*64 + (s >> 5))) * 4096
                       + (d >> 4) * 512
                       + (((s & 31) >> 3)*16 + (d & 15)) * 8 + (s & 7);
            outC[off] = (bf16)v;
          }
        } else {                           // Q fragment-major
          const int bb = rowg >> 11, q = rowg & 2047;
          const int hh = col >> 7, d = col & 127;
          size_t off = ((size_t)((bb*16 + hh)*64 + (q >> 5))) * 4096
                     + ((d >> 5)*2 + ((q >> 4) & 1)) * 512
                     + (((d >> 3) & 3)*16 + (q & 15)) * 8 + (d & 7);
          outB[off] = (bf16)v;
        }
      }
    }
  }
}

__global__ __launch_bounds__(256)
void gemm_one(const bf16* __restrict__ A, const bf16* __restrict__ Wt,
              const float* __restrict__ bias, const float* __restrict__ bias2,
              int nsplit, const bf16* __restrict__ resid,
              bf16* __restrict__ outB, bf16* __restrict__ outC,
              int N, int K, int relu, float oscale, int mode)
{
  __shared__ __align__(16) bf16 As[2*128*32];
  __shared__ __align__(16) bf16 Bs[2*128*32];
  gemm_body(A, Wt, bias, bias2, nsplit, resid, outB, outC, N, K, relu, oscale,
            mode, blockIdx.y*128, blockIdx.x*128, As, Bs);
}

// Two independent GEMMs in one launch (z selects): Q-proj (frag-major) + lin1.
__global__ __launch_bounds__(256)
void gemm_dual(const bf16* __restrict__ A0, const bf16* __restrict__ W0,
               const float* __restrict__ b0, bf16* __restrict__ o0,
               int relu0, float s0,
               const bf16* __restrict__ A1, const bf16* __restrict__ W1,
               const float* __restrict__ b1, bf16* __restrict__ o1,
               int relu1, float s1, int N, int K)
{
  __shared__ __align__(16) bf16 As[2*128*32];
  __shared__ __align__(16) bf16 Bs[2*128*32];
  if (blockIdx.z == 0)
    gemm_body(A0, W0, b0, b0, 1<<30, nullptr, o0, nullptr, N, K, relu0, s0,
              2 /*Q frag*/, blockIdx.y*128, blockIdx.x*128, As, Bs);
  else
    gemm_body(A1, W1, b1, b1, 1<<30, nullptr, o1, nullptr, N, K, relu1, s1,
              0, blockIdx.y*128, blockIdx.x*128, As, Bs);
}

// ---------------------------------------------------------------------------
// GQA attention PARTIAL, round-12:
//  * Q/K/V in FRAGMENT-MAJOR global layout (written by producer GEMMs):
//    every glds16 is a CONTIGUOUS 1KB transfer (64 lanes x 16B linear) --
//    the 16-line scatter of the row-major layout is gone. Q register loads
//    fully coalesced.
//  * 3-buffer, depth-2 pipeline with COUNTED vmcnt (T3/T4): raw s_barrier +
//    s_waitcnt vmcnt(4) (vmcnt(0) only on the last iter). Two tiles of
//    loads stay in flight across barriers.
//  * swapped QK^T (mfma(K,Q)); PV A-fragment via pull-model __shfl
//    transpose (proven in round-11).
//  * s_setprio(1) around MFMA clusters.
// Grid (16 qt, 16 h, B*2 s-halves) = 1024 blocks. LDS 48KB -> 3 blocks/CU.
// ---------------------------------------------------------------------------
__global__ __launch_bounds__(256)
void attn_partial(const bf16* __restrict__ QF, const bf16* __restrict__ KF,
                  const bf16* __restrict__ VF, bf16* __restrict__ OpBase,
                  float* __restrict__ LsBase)
{
  __shared__ __align__(16) bf16 Ks[3*4096];
  __shared__ __align__(16) bf16 Vs[3*4096];
  const int tid = threadIdx.x;
  const int lane = tid & 63, w = tid >> 6;
  const int quad = lane >> 4, l16 = lane & 15;
  const int qt = blockIdx.x, h = blockIdx.y;
  const int b = blockIdx.z >> 1, sh = blockIdx.z & 1;
  const int kv = h >> 2;                 // G = 4
  const int qbase = qt * 128 + w * 32;

  bf16*  Op = OpBase + (size_t)sh * 8388608;        // +16 MiB half stride
  float* Lp = LsBase + (size_t)sh * (B_*NH_*S_);

  const bf16* Ktile = KF + ((size_t)((b*4 + kv) * 64)) * 4096;
  const bf16* Vtile = VF + ((size_t)((b*4 + kv) * 64)) * 4096;
  const bf16* Qt    = QF + ((size_t)((b*16 + h) * 64 + (qbase >> 5))) * 4096;

  const f32x4 fz = {0.f, 0.f, 0.f, 0.f};

  bf16x8 qf[2][4];
  #pragma unroll
  for (int i = 0; i < 2; i++)
    #pragma unroll
    for (int kt = 0; kt < 4; kt++)
      qf[i][kt] = *(const bf16x8*)(Qt + (kt*2 + i)*512 + lane*8);

  f32x4 o[2][8];
  #pragma unroll
  for (int i = 0; i < 2; i++)
    #pragma unroll
    for (int n = 0; n < 8; n++) o[i][n] = fz;
  float lsum[2] = {0.f, 0.f};

  // wave w stages K chunks 2w,2w+1 and V chunks w,4+w; all contiguous 1KB
  auto stageKV = [&](int nb, int t5) {
    const bf16* kt_ = Ktile + (size_t)t5 * 4096;
    const bf16* vt_ = Vtile + (size_t)t5 * 4096;
    bf16* Kb = Ks + nb*4096;
    bf16* Vb = Vs + nb*4096;
    glds16(kt_ + (w*2+0)*512 + lane*8, Kb + (w*2+0)*512 + lane*8);
    glds16(kt_ + (w*2+1)*512 + lane*8, Kb + (w*2+1)*512 + lane*8);
    glds16(vt_ + (w    )*512 + lane*8, Vb + (w    )*512 + lane*8);
    glds16(vt_ + (4+w  )*512 + lane*8, Vb + (4+w  )*512 + lane*8);
  };

  const int t5b = sh * 32;               // s5 base for this half
  stageKV(0, t5b);
  stageKV(1, t5b + 1);

  const int NIT = 32;
  int cur = 0;
  for (int it = 0; it < NIT; it++) {
    // counted wait: my stage(it) loads done; stage(it+1)'s 4 may remain
    if (it < NIT - 1) { asm volatile("s_waitcnt vmcnt(4)" ::: "memory"); }
    else              { asm volatile("s_waitcnt vmcnt(0)" ::: "memory"); }
    __builtin_amdgcn_sched_barrier(0);
    __builtin_amdgcn_s_barrier();        // all waves' stage(it) complete
    __builtin_amdgcn_sched_barrier(0);
    if (it + 2 < NIT) {
      int pre = cur + 2; if (pre >= 3) pre -= 3;
      stageKV(pre, t5b + it + 2);
    }

    // ---- QK^T, swapped operands: sa[i][half] has q=l16, s=half*16+quad*4+r
    const bf16* Kb = Ks + cur*4096;
    const bf16* Vb = Vs + cur*4096;
    f32x4 sa[2][2];
    sa[0][0] = fz; sa[0][1] = fz; sa[1][0] = fz; sa[1][1] = fz;
    __builtin_amdgcn_s_setprio(1);
    #pragma unroll
    for (int kt = 0; kt < 4; kt++) {
      bf16x8 kf0 = *(const bf16x8*)(Kb + (kt*2+0)*512 + lane*8);
      bf16x8 kf1 = *(const bf16x8*)(Kb + (kt*2+1)*512 + lane*8);
      #pragma unroll
      for (int i = 0; i < 2; i++) {
        sa[i][0] = mfma16(kf0, qf[i][kt], sa[i][0]);
        sa[i][1] = mfma16(kf1, qf[i][kt], sa[i][1]);
      }
    }
    __builtin_amdgcn_s_setprio(0);

    // ---- softmax numerator + in-register transpose to PV A-fragments
    bf16x8 pf[2];
    #pragma unroll
    for (int i = 0; i < 2; i++) {
      float p[2][4];
      #pragma unroll
      for (int nt = 0; nt < 2; nt++)
        #pragma unroll
        for (int r = 0; r < 4; r++) {
          p[nt][r] = exp2f(sa[i][nt][r]);   // Q pre-scaled by 1/sqrt(d)*log2e
          lsum[i] += p[nt][r];
        }
      // source: lane (q=l16, quad') holds s = quad'*4+r (nt0), 16+quad'*4+r (nt1)
      unsigned Apk = pk2(p[0][0], p[0][1]);   // s = q'*4 + {0,1}
      unsigned Bpk = pk2(p[0][2], p[0][3]);   // s = q'*4 + {2,3}
      unsigned Cpk = pk2(p[1][0], p[1][1]);   // s = 16 + q'*4 + {0,1}
      unsigned Dpk = pk2(p[1][2], p[1][3]);   // s = 16 + q'*4 + {2,3}
      // target: lane (q=l16, quad) needs s = quad*8 + 0..7 as 4 dwords.
      const int srcL = l16 + ((quad & 1) << 5);
      const bool hi = (quad >= 2);
      const unsigned a0 = __shfl(Apk, srcL),      b0 = __shfl(Bpk, srcL);
      const unsigned a1 = __shfl(Apk, srcL + 16), b1 = __shfl(Bpk, srcL + 16);
      const unsigned c0 = __shfl(Cpk, srcL),      d0 = __shfl(Dpk, srcL);
      const unsigned c1 = __shfl(Cpk, srcL + 16), d1 = __shfl(Dpk, srcL + 16);
      u32x4 t;
      t.x = hi ? c0 : a0;
      t.y = hi ? d0 : b0;
      t.z = hi ? c1 : a1;
      t.w = hi ? d1 : b1;
      pf[i] = __builtin_bit_cast(bf16x8, t);
    }

    // ---- PV
    __builtin_amdgcn_s_setprio(1);
    #pragma unroll
    for (int nt = 0; nt < 8; nt++) {
      bf16x8 vf = *(const bf16x8*)(Vb + nt*512 + lane*8);
      o[0][nt] = mfma16(pf[0], vf, o[0][nt]);
      o[1][nt] = mfma16(pf[1], vf, o[1][nt]);
    }
    __builtin_amdgcn_s_setprio(0);

    cur = (cur == 2) ? 0 : cur + 1;
  }

  bf16* op = Op + ((size_t)b * S_ + qbase) * H_ + h * HD_;
  #pragma unroll
  for (int i = 0; i < 2; i++)
    #pragma unroll
    for (int nt = 0; nt < 8; nt++)
      #pragma unroll
      for (int r = 0; r < 4; r++)
        op[(size_t)(i*16 + quad*4 + r) * H_ + nt*16 + l16] = (bf16)o[i][nt][r];

  // row-sums: lane holds partial over its 8 s-values; reduce across quads
  float* lp = Lp + (size_t)(b * NH_ + h) * S_ + qbase;
  #pragma unroll
  for (int i = 0; i < 2; i++) {
    float s = lsum[i];
    s += __shfl_xor(s, 16);
    s += __shfl_xor(s, 32);
    if (lane < 16) lp[i*16 + lane] = s;
  }
}

// ---------------------------------------------------------------------------
// ctx = (O0+O1)/(L0+L1); one block per (b,s) row.
// ---------------------------------------------------------------------------
__global__ __launch_bounds__(256)
void attn_combine(const bf16* __restrict__ O0, const bf16* __restrict__ O1,
                  const float* __restrict__ L0, const float* __restrict__ L1,
                  bf16* __restrict__ ctx)
{
  const int row = blockIdx.x;              // b*S + s
  const int b = row >> 11, s = row & 2047;
  const int tid = threadIdx.x;
  const int h = tid >> 4;
  const size_t idx = (size_t)row * H_ + tid * 8;
  const size_t li  = (size_t)(b * NH_ + h) * S_ + s;
  const float rinv = 1.f / (L0[li] + L1[li]);
  bf16x8 a = *(const bf16x8*)(O0 + idx);
  bf16x8 c = *(const bf16x8*)(O1 + idx);
  bf16x8 o;
  #pragma unroll
  for (int k = 0; k < 8; k++)
    o[k] = (bf16)(((float)a[k] + (float)c[k]) * rinv);
  *(bf16x8*)(ctx + idx) = o;
}

// ---------------------------------------------------------------------------
// y = LN(a + hidden)*gamma + beta. fp32 out.
// ---------------------------------------------------------------------------
__global__ __launch_bounds__(256)
void ln_fused(const bf16* __restrict__ a, const float* __restrict__ hidden,
              const float* __restrict__ gamma, const float* __restrict__ beta,
              float* __restrict__ out)
{
  __shared__ float red[8];
  const int row = blockIdx.x;
  const bf16*  pa = a      + (size_t)row * H_;
  const float* pb = hidden + (size_t)row * H_;
  float x[8]; float s = 0.f, s2 = 0.f;
  #pragma unroll
  for (int j = 0; j < 8; j++) {
    int c = threadIdx.x + j*256;
    float v = (float)pa[c] + pb[c];
    x[j] = v; s += v; s2 += v*v;
  }
  #pragma unroll
  for (int off = 1; off < 64; off <<= 1) {
    s  += __shfl_xor(s,  off);
    s2 += __shfl_xor(s2, off);
  }
  const int wv = threadIdx.x >> 6;
  if ((threadIdx.x & 63) == 0) { red[wv] = s; red[4 + wv] = s2; }
  __syncthreads();
  s  = red[0] + red[1] + red[2] + red[3];
  s2 = red[4] + red[5] + red[6] + red[7];
  const float mu   = s * (1.0f / H_);
  const float var  = s2 * (1.0f / H_) - mu * mu;
  const float rstd = rsqrtf(var + 1e-12f);
  float* po = out + (size_t)row * H_;
  #pragma unroll
  for (int j = 0; j < 8; j++) {
    int c = threadIdx.x + j*256;
    po[c] = ((x[j] - mu) * rstd) * gamma[c] + beta[c];
  }
}

// ---------------------------------------------------------------------------
extern "C" void kernel_launch(void* const* d_in, const int* in_sizes, int n_in,
                              void* d_out, int out_size, void* d_ws, size_t ws_size,
                              hipStream_t stream)
{
  (void)in_sizes; (void)n_in; (void)out_size; (void)ws_size;
  const float* hidden = (const float*)d_in[0];
  const float* source = (const float*)d_in[1];
  const float* Wq = (const float*)d_in[2];
  const float* bq = (const float*)d_in[3];
  const float* Wk = (const float*)d_in[4];
  const float* bk = (const float*)d_in[5];
  const float* Wv = (const float*)d_in[6];
  const float* bv = (const float*)d_in[7];
  const float* Wd = (const float*)d_in[8];
  const float* bd = (const float*)d_in[9];
  const float* W1 = (const float*)d_in[10];
  const float* b1 = (const float*)d_in[11];
  const float* W2 = (const float*)d_in[12];
  const float* b2 = (const float*)d_in[13];
  const float* gamma = (const float*)d_in[14];
  const float* beta  = (const float*)d_in[15];

  // Workspace (100 MiB):
  //   [0,16):  hb (t0-t1) -> Pb (t2-t3) -> O0 (t5-t6)
  //   [16,32): sb (t0-t1) -> O1 (t5-t6)
  //   [32,48): QF (t1-t5) -> oFb (t7-t8)
  //   [48,56): Wqt (t0-t1) -> Ls (t5-t6)
  //   [56,64): W2t (t0-t2) -> ctx lo (t6-t7)
  //   [64,72): W1t (t0-t1) -> ctx hi
  //   [72,80): Wdt (t0-t7)
  //   [80,82): Wkt; [82,84): Wvt  (contiguous -> fused KV B-matrix)
  //   [84,100): Pl1 (t1-t2) -> KF [84,88) + VF [88,92) (t3-t5)
  char* ws = (char*)d_ws;
  const size_t M = 1048576;
  bf16*  rHB = (bf16*)(ws + 0*M);
  bf16*  rSB = (bf16*)(ws + 16*M);
  bf16*  QF  = (bf16*)(ws + 32*M);
  bf16*  Wqt = (bf16*)(ws + 48*M);
  bf16*  W2t = (bf16*)(ws + 56*M);
  bf16*  W1t = (bf16*)(ws + 64*M);
  bf16*  Wdt = (bf16*)(ws + 72*M);
  bf16*  Wkt = (bf16*)(ws + 80*M);
  bf16*  Wvt = (bf16*)(ws + 82*M);
  bf16*  Pl1 = (bf16*)(ws + 84*M);
  bf16*  KF  = (bf16*)(ws + 84*M);
  bf16*  VF  = (bf16*)(ws + 88*M);
  float* Ls  = (float*)(ws + 48*M);
  bf16*  Pb  = rHB;
  bf16*  O0  = rHB;
  bf16*  ctx = (bf16*)(ws + 56*M);
  bf16*  oFb = QF;

  // t0: everything input-independent in ONE launch
  prep<<<34816, 256, 0, stream>>>(Wq, W1, W2, Wd, Wk, Wv, hidden, source,
                                  Wqt, W1t, W2t, Wdt, Wkt, Wvt, rHB, rSB);
  // t1: fused Q-proj (pre-scaled, fragment-major out) + lin1(relu)
  gemm_dual<<<dim3(16,32,2), 256, 0, stream>>>(
      rHB, Wqt, bq, QF,  0, QSCALE,
      rSB, W1t, b1, Pl1, 1, 1.0f, 2048, 2048);
  // t2: lin2 with +Pl1 residual -> Pb
  gemm_one<<<dim3(16,32), 256, 0, stream>>>(Pl1, W2t, b2, b2, 1<<30, Pl1,
                                            Pb, nullptr, 2048, 2048, 0, 1.0f, 0);
  // t3: fused K|V projection -> fragment-major KF / VF (transpose_v deleted)
  gemm_one<<<dim3(8,32), 256, 0, stream>>>(Pb, Wkt, bk, bv, 512, nullptr,
                                           KF, VF, 1024, 2048, 0, 1.0f, 1);
  // t5: attention partials
  attn_partial<<<dim3(16,16,4), 256, 0, stream>>>(QF, KF, VF, O0, Ls);
  // t6: combine -> ctx
  attn_combine<<<4096, 256, 0, stream>>>(O0, rSB, Ls, Ls + B_*NH_*S_, ctx);
  // t7: out proj
  gemm_one<<<dim3(16,32), 256, 0, stream>>>(ctx, Wdt, bd, bd, 1<<30, nullptr,
                                            oFb, nullptr, 2048, 2048, 0, 1.0f, 0);
  // t8
  ln_fused<<<4096, 256, 0, stream>>>(oFb, hidden, gamma, beta, (float*)d_out);
}

// Round 5
// 585.897 us; speedup vs baseline: 1.0965x; 1.0196x over previous
//
#include <hip/hip_runtime.h>
#include <hip/hip_bf16.h>

typedef __bf16 bf16;
typedef __bf16 bf16x2 __attribute__((ext_vector_type(2)));
typedef __bf16 bf16x4 __attribute__((ext_vector_type(4)));
typedef __bf16 bf16x8 __attribute__((ext_vector_type(8)));
typedef float  f32x4  __attribute__((ext_vector_type(4)));
typedef unsigned int u32x4 __attribute__((ext_vector_type(4)));

#define H_   2048
#define S_   2048
#define B_   2
#define NH_  16
#define NKV_ 4
#define HD_  128
#define KVS  1024   /* fused K|V projection row width */

// 1/sqrt(HD) * log2(e): folded into Q so attention can use exp2 directly
#define QSCALE 0.12751743f

__device__ __forceinline__ f32x4 mfma16(bf16x8 a, bf16x8 b, f32x4 c) {
  return __builtin_amdgcn_mfma_f32_16x16x32_bf16(a, b, c, 0, 0, 0);
}

// async global->LDS, 16B per lane (m97 pattern; LDS dst lane-contiguous)
typedef __attribute__((address_space(3))) unsigned int lds_u32_t;
typedef const __attribute__((address_space(1))) unsigned int glb_u32_t;
__device__ __forceinline__ void glds16(const bf16* g, bf16* l) {
  __builtin_amdgcn_global_load_lds((glb_u32_t*)g, (lds_u32_t*)l, 16, 0, 0);
}

// pack two f32 -> one dword of 2 bf16 (lo = first arg)
__device__ __forceinline__ unsigned pk2(float a, float b) {
  bf16x2 v = { (bf16)a, (bf16)b };
  return __builtin_bit_cast(unsigned, v);
}

// bijective XCD-chunk swizzle (m204): consecutive orig ids round-robin XCDs;
// remap so each XCD owns a contiguous chunk -> panel reuse stays in one L2.
__device__ __forceinline__ int xcd_swz(int orig, int nwg) {
  const int q = nwg >> 3, r = nwg & 7;
  const int xcd = orig & 7, off = orig >> 3;
  return (xcd < r ? xcd * (q + 1) : r * (q + 1) + (xcd - r) * q) + off;
}

// ---------------------------------------------------------------------------
// Fragment-major layouts (tile = 32 rows of s|q x 128 d = 4096 bf16 = 8KB,
// 8 chunks x 512 elems; chunk byte range is CONTIGUOUS 1KB = 64 lanes x 16B):
//  K/Q tile elem (r in 0..31, d in 0..127):
//    chunk = (d>>5)*2 + ((r>>4)&1); lane = ((d>>3)&3)*16 + (r&15); e = d&7
//  V tile elem (s in 0..31, d in 0..127)  [V^T fragments for PV]:
//    chunk = d>>4;  lane = ((s&31)>>3)*16 + (d&15);  e = s&7
// Tile index: K/V: ((b*4+kv)*64 + (s>>5));  Q: ((b*16+h)*64 + (q>>5)).
// ---------------------------------------------------------------------------

// ---------------------------------------------------------------------------
// PREP mega-kernel: both activation converts + all six weight transposes.
// ---------------------------------------------------------------------------
__global__ __launch_bounds__(256)
void prep(const float* __restrict__ Wq, const float* __restrict__ W1,
          const float* __restrict__ W2, const float* __restrict__ Wd,
          const float* __restrict__ Wk, const float* __restrict__ Wv,
          const float* __restrict__ hidden, const float* __restrict__ source,
          bf16* __restrict__ Wqt, bf16* __restrict__ W1t,
          bf16* __restrict__ W2t, bf16* __restrict__ Wdt,
          bf16* __restrict__ Wkt, bf16* __restrict__ Wvt,
          bf16* __restrict__ hb,  bf16* __restrict__ sb)
{
  __shared__ bf16 t[32][33];
  int idx = blockIdx.x;
  if (idx < 16384) {                       // activation converts
    const float* in = (idx < 8192) ? hidden : source;
    bf16*       out = (idx < 8192) ? hb : sb;
    const int i = idx & 8191;
    const size_t off = ((size_t)i * 256 + threadIdx.x) * 4;
    const float4 v = *(const float4*)(in + off);
    bf16x4 o = { (bf16)v.x, (bf16)v.y, (bf16)v.z, (bf16)v.w };
    *(bf16x4*)(out + off) = o;
    return;
  }
  idx -= 16384;
  const float* in; bf16* out; int N;
  if      (idx < 4096)  { in = Wq; out = Wqt; N = 2048; }
  else if (idx < 8192)  { in = W1; out = W1t; N = 2048; idx -= 4096; }
  else if (idx < 12288) { in = W2; out = W2t; N = 2048; idx -= 8192; }
  else if (idx < 16384) { in = Wd; out = Wdt; N = 2048; idx -= 12288; }
  else if (idx < 17408) { in = Wk; out = Wkt; N = 512;  idx -= 16384; }
  else                  { in = Wv; out = Wvt; N = 512;  idx -= 17408; }
  const int K = 2048;
  const int tx = threadIdx.x & 31, ty = threadIdx.x >> 5;
  const int k0 = (idx & 63) * 32, n0 = (idx >> 6) * 32;
  #pragma unroll
  for (int i = 0; i < 4; i++)
    t[ty + i*8][tx] = (bf16)in[(size_t)(k0 + ty + i*8) * N + n0 + tx];
  __syncthreads();
  #pragma unroll
  for (int i = 0; i < 4; i++)
    out[(size_t)(n0 + ty + i*8) * K + k0 + tx] = t[tx][ty + i*8];
}

// ---------------------------------------------------------------------------
// 128x128-tile bf16 MFMA GEMM body.
// Round-5: 3-buffer ring, depth-2 prefetch, COUNTED vmcnt(4) + raw s_barrier
// (exact schedule proven in attn round-4: wait own stage(it), barrier, issue
// stage(it+2) into the buffer compute(it-1) released before this barrier).
// bias split: col < nsplit -> bias[col], else bias2[col-nsplit] (fused KV).
// mode: 0 = row-major; 1 = KV fragment-major (outB=KF, outC=VF); 2 = Q frag.
// ---------------------------------------------------------------------------
__device__ __forceinline__
void gemm_body(const bf16* __restrict__ A, const bf16* __restrict__ Wt,
               const float* __restrict__ bias, const float* __restrict__ bias2,
               int nsplit, const bf16* __restrict__ resid,
               bf16* __restrict__ outB, bf16* __restrict__ outC,
               int N, int K, int relu, float oscale, int mode,
               int m0, int n0, bf16* As, bf16* Bs)
{
  const int tid  = threadIdx.x;
  const int lane = tid & 63;
  const int w    = tid >> 6;
  const int wm = w & 1, wn = w >> 1;
  const int quad = lane >> 4, l16 = lane & 15;
  const int g_r = lane >> 2;
  const int g_c = (lane & 3) * 8;

  const f32x4 fz = {0.f, 0.f, 0.f, 0.f};
  f32x4 acc[4][4];
  #pragma unroll
  for (int i = 0; i < 4; i++)
    #pragma unroll
    for (int j = 0; j < 4; j++) acc[i][j] = fz;

  auto stage = [&](int nb, int k0) {
    #pragma unroll
    for (int i = 0; i < 2; i++) {
      const int rb = (w*2 + i) * 16;
      glds16(A  + (size_t)(m0 + rb + g_r) * K + k0 + g_c, As + nb*4096 + rb*32 + lane*8);
      glds16(Wt + (size_t)(n0 + rb + g_r) * K + k0 + g_c, Bs + nb*4096 + rb*32 + lane*8);
    }
  };

  stage(0, 0);
  stage(1, 32);
  const int NK = K >> 5;   // 64
  int cur = 0;
  for (int it = 0; it < NK; it++) {
    // own stage(it) complete; stage(it+1)'s 4 loads may stay in flight
    if (it < NK - 1) { asm volatile("s_waitcnt vmcnt(4)" ::: "memory"); }
    else             { asm volatile("s_waitcnt vmcnt(0)" ::: "memory"); }
    __builtin_amdgcn_sched_barrier(0);
    __builtin_amdgcn_s_barrier();        // all waves' stage(it) complete
    __builtin_amdgcn_sched_barrier(0);
    if (it + 2 < NK) {
      int pre = cur + 2; if (pre >= 3) pre -= 3;
      stage(pre, (it + 2) << 5);
    }
    bf16x8 af[4], bfr[4];
    #pragma unroll
    for (int i = 0; i < 4; i++)
      af[i]  = *(const bf16x8*)(As + cur*4096 + (wm*64 + i*16 + l16)*32 + quad*8);
    #pragma unroll
    for (int j = 0; j < 4; j++)
      bfr[j] = *(const bf16x8*)(Bs + cur*4096 + (wn*64 + j*16 + l16)*32 + quad*8);
    #pragma unroll
    for (int i = 0; i < 4; i++)
      #pragma unroll
      for (int j = 0; j < 4; j++)
        acc[i][j] = mfma16(af[i], bfr[j], acc[i][j]);
    cur = (cur == 2) ? 0 : cur + 1;
  }

  // C/D layout: col = lane&15, row = (lane>>4)*4 + reg   [m89/m91]
  #pragma unroll
  for (int i = 0; i < 4; i++) {
    const int row = m0 + wm*64 + i*16 + quad*4;
    #pragma unroll
    for (int j = 0; j < 4; j++) {
      const int col = n0 + wn*64 + j*16 + l16;
      const float bi = (col < nsplit) ? bias[col] : bias2[col - nsplit];
      #pragma unroll
      for (int r = 0; r < 4; r++) {
        float v = acc[i][j][r] + bi;
        if (relu) v = fmaxf(v, 0.f);
        v *= oscale;
        const int rowg = row + r;
        if (mode == 0) {
          size_t idx = (size_t)rowg * N + col;
          if (resid) v += (float)resid[idx];
          outB[idx] = (bf16)v;
        } else if (mode == 1) {            // K|V fragment-major
          const int bb = rowg >> 11, s = rowg & 2047;
          if (col < 512) {
            const int kvq = col >> 7, d = col & 127;
            size_t off = ((size_t)((bb*4 + kvq)*64 + (s >> 5))) * 4096
                       + ((d >> 5)*2 + ((s >> 4) & 1)) * 512
                       + (((d >> 3) & 3)*16 + (s & 15)) * 8 + (d & 7);
            outB[off] = (bf16)v;
          } else {
            const int kvq = (col - 512) >> 7, d = (col - 512) & 127;
            size_t off = ((size_t)((bb*4 + kvq)*64 + (s >> 5))) * 4096
                       + (d >> 4) * 512
                       + (((s & 31) >> 3)*16 + (d & 15)) * 8 + (s & 7);
            outC[off] = (bf16)v;
          }
        } else {                           // Q fragment-major
          const int bb = rowg >> 11, q = rowg & 2047;
          const int hh = col >> 7, d = col & 127;
          size_t off = ((size_t)((bb*16 + hh)*64 + (q >> 5))) * 4096
                     + ((d >> 5)*2 + ((q >> 4) & 1)) * 512
                     + (((d >> 3) & 3)*16 + (q & 15)) * 8 + (d & 7);
          outB[off] = (bf16)v;
        }
      }
    }
  }
}

__global__ __launch_bounds__(256)
void gemm_one(const bf16* __restrict__ A, const bf16* __restrict__ Wt,
              const float* __restrict__ bias, const float* __restrict__ bias2,
              int nsplit, const bf16* __restrict__ resid,
              bf16* __restrict__ outB, bf16* __restrict__ outC,
              int N, int K, int relu, float oscale, int mode)
{
  __shared__ __align__(16) bf16 As[3*4096];
  __shared__ __align__(16) bf16 Bs[3*4096];
  const int nwg = gridDim.x * gridDim.y;
  const int wg = xcd_swz(blockIdx.y * gridDim.x + blockIdx.x, nwg);
  const int bx = wg % gridDim.x, by = wg / gridDim.x;
  gemm_body(A, Wt, bias, bias2, nsplit, resid, outB, outC, N, K, relu, oscale,
            mode, by*128, bx*128, As, Bs);
}

// Two independent GEMMs in one launch (z selects): Q-proj (frag-major) + lin1.
__global__ __launch_bounds__(256)
void gemm_dual(const bf16* __restrict__ A0, const bf16* __restrict__ W0,
               const float* __restrict__ b0, bf16* __restrict__ o0,
               int relu0, float s0,
               const bf16* __restrict__ A1, const bf16* __restrict__ W1,
               const float* __restrict__ b1, bf16* __restrict__ o1,
               int relu1, float s1, int N, int K)
{
  __shared__ __align__(16) bf16 As[3*4096];
  __shared__ __align__(16) bf16 Bs[3*4096];
  const int nwg = gridDim.x * gridDim.y;
  const int wg = xcd_swz(blockIdx.y * gridDim.x + blockIdx.x, nwg);
  const int bx = wg % gridDim.x, by = wg / gridDim.x;
  if (blockIdx.z == 0)
    gemm_body(A0, W0, b0, b0, 1<<30, nullptr, o0, nullptr, N, K, relu0, s0,
              2 /*Q frag*/, by*128, bx*128, As, Bs);
  else
    gemm_body(A1, W1, b1, b1, 1<<30, nullptr, o1, nullptr, N, K, relu1, s1,
              0, by*128, bx*128, As, Bs);
}

// ---------------------------------------------------------------------------
// GQA attention PARTIAL (round-4 structure, + XCD-chunk swizzle):
//  * Q/K/V fragment-major; every glds16 contiguous 1KB.
//  * 3-buffer depth-2 counted-vmcnt pipeline.
//  * swapped QK^T; in-register P transpose via pull-model __shfl.
// Grid (16 qt, 16 h, B*2 s-halves) = 1024 blocks. LDS 48KB -> 3 blocks/CU.
// ---------------------------------------------------------------------------
__global__ __launch_bounds__(256)
void attn_partial(const bf16* __restrict__ QF, const bf16* __restrict__ KF,
                  const bf16* __restrict__ VF, bf16* __restrict__ OpBase,
                  float* __restrict__ LsBase)
{
  __shared__ __align__(16) bf16 Ks[3*4096];
  __shared__ __align__(16) bf16 Vs[3*4096];
  const int tid = threadIdx.x;
  const int lane = tid & 63, w = tid >> 6;
  const int quad = lane >> 4, l16 = lane & 15;
  // XCD swizzle: 16 consecutive ids share (h,b,sh) K/V panels -> chunk them
  const int wg = xcd_swz(((int)blockIdx.z * 16 + (int)blockIdx.y) * 16 + (int)blockIdx.x, 1024);
  const int qt = wg & 15, h = (wg >> 4) & 15;
  const int bz = wg >> 8;
  const int b = bz >> 1, sh = bz & 1;
  const int kv = h >> 2;                 // G = 4
  const int qbase = qt * 128 + w * 32;

  bf16*  Op = OpBase + (size_t)sh * 8388608;        // +16 MiB half stride
  float* Lp = LsBase + (size_t)sh * (B_*NH_*S_);

  const bf16* Ktile = KF + ((size_t)((b*4 + kv) * 64)) * 4096;
  const bf16* Vtile = VF + ((size_t)((b*4 + kv) * 64)) * 4096;
  const bf16* Qt    = QF + ((size_t)((b*16 + h) * 64 + (qbase >> 5))) * 4096;

  const f32x4 fz = {0.f, 0.f, 0.f, 0.f};

  bf16x8 qf[2][4];
  #pragma unroll
  for (int i = 0; i < 2; i++)
    #pragma unroll
    for (int kt = 0; kt < 4; kt++)
      qf[i][kt] = *(const bf16x8*)(Qt + (kt*2 + i)*512 + lane*8);

  f32x4 o[2][8];
  #pragma unroll
  for (int i = 0; i < 2; i++)
    #pragma unroll
    for (int n = 0; n < 8; n++) o[i][n] = fz;
  float lsum[2] = {0.f, 0.f};

  // wave w stages K chunks 2w,2w+1 and V chunks w,4+w; all contiguous 1KB
  auto stageKV = [&](int nb, int t5) {
    const bf16* kt_ = Ktile + (size_t)t5 * 4096;
    const bf16* vt_ = Vtile + (size_t)t5 * 4096;
    bf16* Kb = Ks + nb*4096;
    bf16* Vb = Vs + nb*4096;
    glds16(kt_ + (w*2+0)*512 + lane*8, Kb + (w*2+0)*512 + lane*8);
    glds16(kt_ + (w*2+1)*512 + lane*8, Kb + (w*2+1)*512 + lane*8);
    glds16(vt_ + (w    )*512 + lane*8, Vb + (w    )*512 + lane*8);
    glds16(vt_ + (4+w  )*512 + lane*8, Vb + (4+w  )*512 + lane*8);
  };

  const int t5b = sh * 32;               // tile base for this half
  stageKV(0, t5b);
  stageKV(1, t5b + 1);

  const int NIT = 32;
  int cur = 0;
  for (int it = 0; it < NIT; it++) {
    if (it < NIT - 1) { asm volatile("s_waitcnt vmcnt(4)" ::: "memory"); }
    else              { asm volatile("s_waitcnt vmcnt(0)" ::: "memory"); }
    __builtin_amdgcn_sched_barrier(0);
    __builtin_amdgcn_s_barrier();        // all waves' stage(it) complete
    __builtin_amdgcn_sched_barrier(0);
    if (it + 2 < NIT) {
      int pre = cur + 2; if (pre >= 3) pre -= 3;
      stageKV(pre, t5b + it + 2);
    }

    // ---- QK^T, swapped operands: sa[i][half] has q=l16, s=half*16+quad*4+r
    const bf16* Kb = Ks + cur*4096;
    const bf16* Vb = Vs + cur*4096;
    f32x4 sa[2][2];
    sa[0][0] = fz; sa[0][1] = fz; sa[1][0] = fz; sa[1][1] = fz;
    __builtin_amdgcn_s_setprio(1);
    #pragma unroll
    for (int kt = 0; kt < 4; kt++) {
      bf16x8 kf0 = *(const bf16x8*)(Kb + (kt*2+0)*512 + lane*8);
      bf16x8 kf1 = *(const bf16x8*)(Kb + (kt*2+1)*512 + lane*8);
      #pragma unroll
      for (int i = 0; i < 2; i++) {
        sa[i][0] = mfma16(kf0, qf[i][kt], sa[i][0]);
        sa[i][1] = mfma16(kf1, qf[i][kt], sa[i][1]);
      }
    }
    __builtin_amdgcn_s_setprio(0);

    // ---- softmax numerator + in-register transpose to PV A-fragments
    bf16x8 pf[2];
    #pragma unroll
    for (int i = 0; i < 2; i++) {
      float p[2][4];
      #pragma unroll
      for (int nt = 0; nt < 2; nt++)
        #pragma unroll
        for (int r = 0; r < 4; r++) {
          p[nt][r] = exp2f(sa[i][nt][r]);   // Q pre-scaled by 1/sqrt(d)*log2e
          lsum[i] += p[nt][r];
        }
      // source: lane (q=l16, quad') holds s = quad'*4+r (nt0), 16+quad'*4+r (nt1)
      unsigned Apk = pk2(p[0][0], p[0][1]);   // s = q'*4 + {0,1}
      unsigned Bpk = pk2(p[0][2], p[0][3]);   // s = q'*4 + {2,3}
      unsigned Cpk = pk2(p[1][0], p[1][1]);   // s = 16 + q'*4 + {0,1}
      unsigned Dpk = pk2(p[1][2], p[1][3]);   // s = 16 + q'*4 + {2,3}
      // target: lane (q=l16, quad) needs s = quad*8 + 0..7 as 4 dwords.
      const int srcL = l16 + ((quad & 1) << 5);
      const bool hi = (quad >= 2);
      const unsigned a0 = __shfl(Apk, srcL),      b0 = __shfl(Bpk, srcL);
      const unsigned a1 = __shfl(Apk, srcL + 16), b1 = __shfl(Bpk, srcL + 16);
      const unsigned c0 = __shfl(Cpk, srcL),      d0 = __shfl(Dpk, srcL);
      const unsigned c1 = __shfl(Cpk, srcL + 16), d1 = __shfl(Dpk, srcL + 16);
      u32x4 t;
      t.x = hi ? c0 : a0;
      t.y = hi ? d0 : b0;
      t.z = hi ? c1 : a1;
      t.w = hi ? d1 : b1;
      pf[i] = __builtin_bit_cast(bf16x8, t);
    }

    // ---- PV
    __builtin_amdgcn_s_setprio(1);
    #pragma unroll
    for (int nt = 0; nt < 8; nt++) {
      bf16x8 vf = *(const bf16x8*)(Vb + nt*512 + lane*8);
      o[0][nt] = mfma16(pf[0], vf, o[0][nt]);
      o[1][nt] = mfma16(pf[1], vf, o[1][nt]);
    }
    __builtin_amdgcn_s_setprio(0);

    cur = (cur == 2) ? 0 : cur + 1;
  }

  bf16* op = Op + ((size_t)b * S_ + qbase) * H_ + h * HD_;
  #pragma unroll
  for (int i = 0; i < 2; i++)
    #pragma unroll
    for (int nt = 0; nt < 8; nt++)
      #pragma unroll
      for (int r = 0; r < 4; r++)
        op[(size_t)(i*16 + quad*4 + r) * H_ + nt*16 + l16] = (bf16)o[i][nt][r];

  // row-sums: lane holds partial over its 8 s-values; reduce across quads
  float* lp = Lp + (size_t)(b * NH_ + h) * S_ + qbase;
  #pragma unroll
  for (int i = 0; i < 2; i++) {
    float s = lsum[i];
    s += __shfl_xor(s, 16);
    s += __shfl_xor(s, 32);
    if (lane < 16) lp[i*16 + lane] = s;
  }
}

// ---------------------------------------------------------------------------
// ctx = (O0+O1)/(L0+L1); one block per (b,s) row.
// ---------------------------------------------------------------------------
__global__ __launch_bounds__(256)
void attn_combine(const bf16* __restrict__ O0, const bf16* __restrict__ O1,
                  const float* __restrict__ L0, const float* __restrict__ L1,
                  bf16* __restrict__ ctx)
{
  const int row = blockIdx.x;              // b*S + s
  const int b = row >> 11, s = row & 2047;
  const int tid = threadIdx.x;
  const int h = tid >> 4;
  const size_t idx = (size_t)row * H_ + tid * 8;
  const size_t li  = (size_t)(b * NH_ + h) * S_ + s;
  const float rinv = 1.f / (L0[li] + L1[li]);
  bf16x8 a = *(const bf16x8*)(O0 + idx);
  bf16x8 c = *(const bf16x8*)(O1 + idx);
  bf16x8 o;
  #pragma unroll
  for (int k = 0; k < 8; k++)
    o[k] = (bf16)(((float)a[k] + (float)c[k]) * rinv);
  *(bf16x8*)(ctx + idx) = o;
}

// ---------------------------------------------------------------------------
// y = LN(a + hidden)*gamma + beta. fp32 out.
// ---------------------------------------------------------------------------
__global__ __launch_bounds__(256)
void ln_fused(const bf16* __restrict__ a, const float* __restrict__ hidden,
              const float* __restrict__ gamma, const float* __restrict__ beta,
              float* __restrict__ out)
{
  __shared__ float red[8];
  const int row = blockIdx.x;
  const bf16*  pa = a      + (size_t)row * H_;
  const float* pb = hidden + (size_t)row * H_;
  float x[8]; float s = 0.f, s2 = 0.f;
  #pragma unroll
  for (int j = 0; j < 8; j++) {
    int c = threadIdx.x + j*256;
    float v = (float)pa[c] + pb[c];
    x[j] = v; s += v; s2 += v*v;
  }
  #pragma unroll
  for (int off = 1; off < 64; off <<= 1) {
    s  += __shfl_xor(s,  off);
    s2 += __shfl_xor(s2, off);
  }
  const int wv = threadIdx.x >> 6;
  if ((threadIdx.x & 63) == 0) { red[wv] = s; red[4 + wv] = s2; }
  __syncthreads();
  s  = red[0] + red[1] + red[2] + red[3];
  s2 = red[4] + red[5] + red[6] + red[7];
  const float mu   = s * (1.0f / H_);
  const float var  = s2 * (1.0f / H_) - mu * mu;
  const float rstd = rsqrtf(var + 1e-12f);
  float* po = out + (size_t)row * H_;
  #pragma unroll
  for (int j = 0; j < 8; j++) {
    int c = threadIdx.x + j*256;
    po[c] = ((x[j] - mu) * rstd) * gamma[c] + beta[c];
  }
}

// ---------------------------------------------------------------------------
extern "C" void kernel_launch(void* const* d_in, const int* in_sizes, int n_in,
                              void* d_out, int out_size, void* d_ws, size_t ws_size,
                              hipStream_t stream)
{
  (void)in_sizes; (void)n_in; (void)out_size; (void)ws_size;
  const float* hidden = (const float*)d_in[0];
  const float* source = (const float*)d_in[1];
  const float* Wq = (const float*)d_in[2];
  const float* bq = (const float*)d_in[3];
  const float* Wk = (const float*)d_in[4];
  const float* bk = (const float*)d_in[5];
  const float* Wv = (const float*)d_in[6];
  const float* bv = (const float*)d_in[7];
  const float* Wd = (const float*)d_in[8];
  const float* bd = (const float*)d_in[9];
  const float* W1 = (const float*)d_in[10];
  const float* b1 = (const float*)d_in[11];
  const float* W2 = (const float*)d_in[12];
  const float* b2 = (const float*)d_in[13];
  const float* gamma = (const float*)d_in[14];
  const float* beta  = (const float*)d_in[15];

  // Workspace (100 MiB):
  //   [0,16):  hb (t0-t1) -> Pb (t2-t3) -> O0 (t5-t6)
  //   [16,32): sb (t0-t1) -> O1 (t5-t6)
  //   [32,48): QF (t1-t5) -> oFb (t7-t8)
  //   [48,56): Wqt (t0-t1) -> Ls (t5-t6)
  //   [56,64): W2t (t0-t2) -> ctx lo (t6-t7)
  //   [64,72): W1t (t0-t1) -> ctx hi
  //   [72,80): Wdt (t0-t7)
  //   [80,82): Wkt; [82,84): Wvt  (contiguous -> fused KV B-matrix)
  //   [84,100): Pl1 (t1-t2) -> KF [84,88) + VF [88,92) (t3-t5)
  char* ws = (char*)d_ws;
  const size_t M = 1048576;
  bf16*  rHB = (bf16*)(ws + 0*M);
  bf16*  rSB = (bf16*)(ws + 16*M);
  bf16*  QF  = (bf16*)(ws + 32*M);
  bf16*  Wqt = (bf16*)(ws + 48*M);
  bf16*  W2t = (bf16*)(ws + 56*M);
  bf16*  W1t = (bf16*)(ws + 64*M);
  bf16*  Wdt = (bf16*)(ws + 72*M);
  bf16*  Wkt = (bf16*)(ws + 80*M);
  bf16*  Wvt = (bf16*)(ws + 82*M);
  bf16*  Pl1 = (bf16*)(ws + 84*M);
  bf16*  KF  = (bf16*)(ws + 84*M);
  bf16*  VF  = (bf16*)(ws + 88*M);
  float* Ls  = (float*)(ws + 48*M);
  bf16*  Pb  = rHB;
  bf16*  O0  = rHB;
  bf16*  ctx = (bf16*)(ws + 56*M);
  bf16*  oFb = QF;

  // t0: everything input-independent in ONE launch
  prep<<<34816, 256, 0, stream>>>(Wq, W1, W2, Wd, Wk, Wv, hidden, source,
                                  Wqt, W1t, W2t, Wdt, Wkt, Wvt, rHB, rSB);
  // t1: fused Q-proj (pre-scaled, fragment-major out) + lin1(relu)
  gemm_dual<<<dim3(16,32,2), 256, 0, stream>>>(
      rHB, Wqt, bq, QF,  0, QSCALE,
      rSB, W1t, b1, Pl1, 1, 1.0f, 2048, 2048);
  // t2: lin2 with +Pl1 residual -> Pb
  gemm_one<<<dim3(16,32), 256, 0, stream>>>(Pl1, W2t, b2, b2, 1<<30, Pl1,
                                            Pb, nullptr, 2048, 2048, 0, 1.0f, 0);
  // t3: fused K|V projection -> fragment-major KF / VF
  gemm_one<<<dim3(8,32), 256, 0, stream>>>(Pb, Wkt, bk, bv, 512, nullptr,
                                           KF, VF, 1024, 2048, 0, 1.0f, 1);
  // t5: attention partials
  attn_partial<<<dim3(16,16,4), 256, 0, stream>>>(QF, KF, VF, O0, Ls);
  // t6: combine -> ctx
  attn_combine<<<4096, 256, 0, stream>>>(O0, rSB, Ls, Ls + B_*NH_*S_, ctx);
  // t7: out proj
  gemm_one<<<dim3(16,32), 256, 0, stream>>>(ctx, Wdt, bd, bd, 1<<30, nullptr,
                                            oFb, nullptr, 2048, 2048, 0, 1.0f, 0);
  // t8
  ln_fused<<<4096, 256, 0, stream>>>(oFb, hidden, gamma, beta, (float*)d_out);
}